// Round 4
// baseline (1135.841 us; speedup 1.0000x reference)
//
#include <hip/hip_runtime.h>
#include <math.h>

#define FEAT 128
#define NRBF 20
#define NCONV 3
#define PI_F 3.14159265358979323846f

typedef __attribute__((ext_vector_type(8))) short short8;
typedef __attribute__((ext_vector_type(4))) float floatx4;
typedef unsigned short ushort_t;

__device__ inline float b2f(unsigned short u) {
    union { unsigned int i; float f; } c; c.i = ((unsigned int)u) << 16; return c.f;
}
__device__ inline unsigned short f2b(float x) {
    union { float f; unsigned int i; } c; c.f = x;
    unsigned int u = c.i;
    return (unsigned short)((u + 0x7fffu + ((u >> 16) & 1u)) >> 16);
}
__device__ inline float u2f(unsigned int u) {
    union { unsigned int i; float f; } c; c.i = u; return c.f;
}
__device__ inline unsigned int f2u(float x) {
    union { float f; unsigned int i; } c; c.f = x; return c.i;
}

// ---------------------------------------------------------------------------
// Fused 2-layer MLP: out[M,384] = silu(A1 @ W1^T + b1) @ W2^T + b2
// A1 = s[M,128] (phi mode) or [s | norm(vv)] [M,256] (gate mode, vv != null).
// phi mode writes the MERGED 16B gather record cg[m*128+g] (as ushort*):
//   ushort slots 0,1,2 = phi chunks (bf16 hi), slot 3 = vh0 (untouched here),
//   uints 2,3 = v codec (untouched here). Record stride 8 ushorts.
// ---------------------------------------------------------------------------
__global__ __launch_bounds__(256) void mlp_fused_kernel(
    const float* __restrict__ s, const float* __restrict__ vv,
    const ushort_t* __restrict__ W1h, const ushort_t* __restrict__ W1l,
    const float* __restrict__ b1,
    const ushort_t* __restrict__ W2h, const ushort_t* __restrict__ W2l,
    const float* __restrict__ b2,
    ushort_t* __restrict__ out_b, float* __restrict__ out_f,
    int M, int K1, int SP)
{
    __shared__ __align__(16) ushort_t Ah[128 * 40];
    __shared__ __align__(16) ushort_t Al[128 * 40];
    __shared__ __align__(16) ushort_t Wh[128 * 40];
    __shared__ __align__(16) ushort_t Wl[128 * 40];
    __shared__ __align__(16) ushort_t Hh[128 * 136];
    __shared__ __align__(16) ushort_t Hl[128 * 136];

    const int t    = threadIdx.x;
    const int m0   = blockIdx.x * 128;
    const int wv   = t >> 6;
    const int lane = t & 63;
    const int wm   = (wv >> 1) * 64;
    const int wn   = (wv & 1) * 64;
    const int lr   = lane & 15;
    const int lk   = (lane >> 4) * 8;
    const int quad = lane >> 4;
    const int arow = t >> 3;          // 0..31, 4 passes of 32 rows
    const int acol = (t & 7) * 4;     // fp32 x4
    const int wrow = t >> 2;          // 0..63, 2 passes of 64 rows
    const int wcol = (t & 3) * 8;     // ushort x8

    floatx4 acc[4][4] = {};

    // ---- stage 1: h = silu(A1 @ W1^T + b1) ----
    for (int k0 = 0; k0 < K1; k0 += 32) {
        #pragma unroll
        for (int h = 0; h < 4; ++h) {
            int r = arow + h * 32;
            int m = m0 + r; if (m >= M) m = M - 1;   // clamp tail
            float xs[4];
            if (k0 < 128) {
                float4 av = *(const float4*)(s + (long)m * 128 + k0 + acol);
                xs[0] = av.x; xs[1] = av.y; xs[2] = av.z; xs[3] = av.w;
            } else {
                long base = (long)m * 128 + (k0 - 128 + acol);
                float4 a0 = *(const float4*)(vv + base);
                float4 a1 = *(const float4*)(vv + (long)SP + base);
                float4 a2 = *(const float4*)(vv + 2 * (long)SP + base);
                xs[0] = sqrtf(a0.x * a0.x + a1.x * a1.x + a2.x * a2.x);
                xs[1] = sqrtf(a0.y * a0.y + a1.y * a1.y + a2.y * a2.y);
                xs[2] = sqrtf(a0.z * a0.z + a1.z * a1.z + a2.z * a2.z);
                xs[3] = sqrtf(a0.w * a0.w + a1.w * a1.w + a2.w * a2.w);
            }
            unsigned short hh[4], ll[4];
            #pragma unroll
            for (int q = 0; q < 4; ++q) {
                hh[q] = f2b(xs[q]);
                ll[q] = f2b(xs[q] - b2f(hh[q]));
            }
            *(ushort4*)(&Ah[r * 40 + acol]) = make_ushort4(hh[0], hh[1], hh[2], hh[3]);
            *(ushort4*)(&Al[r * 40 + acol]) = make_ushort4(ll[0], ll[1], ll[2], ll[3]);
        }
        #pragma unroll
        for (int h = 0; h < 2; ++h) {
            int r = wrow + h * 64;
            *(uint4*)(&Wh[r * 40 + wcol]) =
                *(const uint4*)(W1h + (long)r * K1 + k0 + wcol);
            *(uint4*)(&Wl[r * 40 + wcol]) =
                *(const uint4*)(W1l + (long)r * K1 + k0 + wcol);
        }
        __syncthreads();
        short8 af[4], alf[4], wf[4], wlf[4];
        #pragma unroll
        for (int i = 0; i < 4; ++i) {
            af[i]  = *(const short8*)(&Ah[(wm + i * 16 + lr) * 40 + lk]);
            alf[i] = *(const short8*)(&Al[(wm + i * 16 + lr) * 40 + lk]);
            wf[i]  = *(const short8*)(&Wh[(wn + i * 16 + lr) * 40 + lk]);
            wlf[i] = *(const short8*)(&Wl[(wn + i * 16 + lr) * 40 + lk]);
        }
        #pragma unroll
        for (int i = 0; i < 4; ++i)
            #pragma unroll
            for (int j = 0; j < 4; ++j) {
                acc[i][j] = __builtin_amdgcn_mfma_f32_16x16x32_bf16(
                    af[i], wf[j], acc[i][j], 0, 0, 0);
                acc[i][j] = __builtin_amdgcn_mfma_f32_16x16x32_bf16(
                    af[i], wlf[j], acc[i][j], 0, 0, 0);
                acc[i][j] = __builtin_amdgcn_mfma_f32_16x16x32_bf16(
                    alf[i], wf[j], acc[i][j], 0, 0, 0);
            }
        __syncthreads();
    }

    // stage-1 epilogue -> h in LDS (hi/lo), C/D layout col=lane&15, row=quad*4+r
    #pragma unroll
    for (int i = 0; i < 4; ++i)
        #pragma unroll
        for (int r = 0; r < 4; ++r) {
            int mrow = wm + i * 16 + quad * 4 + r;
            #pragma unroll
            for (int j = 0; j < 4; ++j) {
                int kcol = wn + j * 16 + lr;
                float x = acc[i][j][r] + b1[kcol];
                x *= 1.f / (1.f + __expf(-x));
                unsigned short hh = f2b(x);
                Hh[mrow * 136 + kcol] = hh;
                Hl[mrow * 136 + kcol] = f2b(x - b2f(hh));
            }
        }

    // ---- stage 2: out = h @ W2^T + b2, 3 n-tiles of 128 ----
    for (int nt = 0; nt < 3; ++nt) {
        #pragma unroll
        for (int i = 0; i < 4; ++i)
            #pragma unroll
            for (int j = 0; j < 4; ++j)
                #pragma unroll
                for (int q = 0; q < 4; ++q) acc[i][j][q] = 0.f;
        for (int k0 = 0; k0 < 128; k0 += 32) {
            __syncthreads();   // guard Wh/Wl overwrite (and H writes on 1st pass)
            #pragma unroll
            for (int h = 0; h < 2; ++h) {
                int r = wrow + h * 64;
                long wo = (long)(nt * 128 + r) * 128;
                *(uint4*)(&Wh[r * 40 + wcol]) = *(const uint4*)(W2h + wo + k0 + wcol);
                *(uint4*)(&Wl[r * 40 + wcol]) = *(const uint4*)(W2l + wo + k0 + wcol);
            }
            __syncthreads();
            short8 af[4], alf[4], wf[4], wlf[4];
            #pragma unroll
            for (int i = 0; i < 4; ++i) {
                af[i]  = *(const short8*)(&Hh[(wm + i * 16 + lr) * 136 + k0 + lk]);
                alf[i] = *(const short8*)(&Hl[(wm + i * 16 + lr) * 136 + k0 + lk]);
                wf[i]  = *(const short8*)(&Wh[(wn + i * 16 + lr) * 40 + lk]);
                wlf[i] = *(const short8*)(&Wl[(wn + i * 16 + lr) * 40 + lk]);
            }
            #pragma unroll
            for (int i = 0; i < 4; ++i)
                #pragma unroll
                for (int j = 0; j < 4; ++j) {
                    acc[i][j] = __builtin_amdgcn_mfma_f32_16x16x32_bf16(
                        af[i], wf[j], acc[i][j], 0, 0, 0);
                    acc[i][j] = __builtin_amdgcn_mfma_f32_16x16x32_bf16(
                        af[i], wlf[j], acc[i][j], 0, 0, 0);
                    acc[i][j] = __builtin_amdgcn_mfma_f32_16x16x32_bf16(
                        alf[i], wf[j], acc[i][j], 0, 0, 0);
                }
        }
        #pragma unroll
        for (int i = 0; i < 4; ++i)
            #pragma unroll
            for (int r = 0; r < 4; ++r) {
                int m = m0 + wm + i * 16 + quad * 4 + r;
                if (m >= M) continue;
                #pragma unroll
                for (int j = 0; j < 4; ++j) {
                    int n = nt * 128 + wn + j * 16 + lr;
                    float x = acc[i][j][r] + b2[n];
                    if (out_b) out_b[(long)m * 1024 + (long)(n & 127) * 8 + nt] = f2b(x);
                    else       out_f[(long)m * 384 + n] = x;
                }
            }
    }
}

// ---------------------------------------------------------------------------
// Pre-split MFMA GEMM (UV only): dual weights, fp32 C0/C1 routing by n-tile.
// ---------------------------------------------------------------------------
__global__ __launch_bounds__(256) void gemm_ps_kernel(
    const ushort_t* __restrict__ Ahg, const ushort_t* __restrict__ Alg,
    const ushort_t* __restrict__ Whi, const ushort_t* __restrict__ Wlo,
    const ushort_t* __restrict__ W2h, const ushort_t* __restrict__ W2l,
    float* __restrict__ C0, float* __restrict__ C1,
    int M, int K)
{
    __shared__ __align__(16) ushort_t Ah[128 * 40];
    __shared__ __align__(16) ushort_t Al[128 * 40];
    __shared__ __align__(16) ushort_t Wh[128 * 40];
    __shared__ __align__(16) ushort_t Wl[128 * 40];
    const int t    = threadIdx.x;
    const int m0   = blockIdx.x * 128;
    const int nt   = blockIdx.y;          // 0 -> U/C0, 1 -> V/C1
    const int wv   = t >> 6;
    const int lane = t & 63;
    const int wm   = (wv >> 1) * 64;
    const int wn   = (wv & 1) * 64;
    const int lr   = lane & 15;
    const int lk   = (lane >> 4) * 8;
    const int srow = t >> 2;
    const int scol = (t & 3) * 8;
    const ushort_t* Wsh = nt ? W2h : Whi;
    const ushort_t* Wsl = nt ? W2l : Wlo;

    floatx4 acc[4][4] = {};

    for (int k0 = 0; k0 < K; k0 += 32) {
        #pragma unroll
        for (int h = 0; h < 2; ++h) {
            int r = srow + h * 64;
            int m = m0 + r; if (m >= M) m = M - 1;
            *(uint4*)(&Ah[r * 40 + scol]) =
                *(const uint4*)(Ahg + (long)m * K + k0 + scol);
            *(uint4*)(&Al[r * 40 + scol]) =
                *(const uint4*)(Alg + (long)m * K + k0 + scol);
            *(uint4*)(&Wh[r * 40 + scol]) =
                *(const uint4*)(Wsh + (long)r * K + k0 + scol);
            *(uint4*)(&Wl[r * 40 + scol]) =
                *(const uint4*)(Wsl + (long)r * K + k0 + scol);
        }
        __syncthreads();
        short8 ah[4], al[4], wh[4], wl[4];
        #pragma unroll
        for (int i = 0; i < 4; ++i) {
            ah[i] = *(const short8*)(&Ah[(wm + i * 16 + lr) * 40 + lk]);
            al[i] = *(const short8*)(&Al[(wm + i * 16 + lr) * 40 + lk]);
            wh[i] = *(const short8*)(&Wh[(wn + i * 16 + lr) * 40 + lk]);
            wl[i] = *(const short8*)(&Wl[(wn + i * 16 + lr) * 40 + lk]);
        }
        #pragma unroll
        for (int i = 0; i < 4; ++i)
            #pragma unroll
            for (int j = 0; j < 4; ++j) {
                acc[i][j] = __builtin_amdgcn_mfma_f32_16x16x32_bf16(
                    ah[i], wh[j], acc[i][j], 0, 0, 0);
                acc[i][j] = __builtin_amdgcn_mfma_f32_16x16x32_bf16(
                    ah[i], wl[j], acc[i][j], 0, 0, 0);
                acc[i][j] = __builtin_amdgcn_mfma_f32_16x16x32_bf16(
                    al[i], wh[j], acc[i][j], 0, 0, 0);
            }
        __syncthreads();
    }

    float* C = nt ? C1 : C0;
    #pragma unroll
    for (int i = 0; i < 4; ++i)
        #pragma unroll
        for (int r = 0; r < 4; ++r) {
            int m = m0 + wm + i * 16 + (lane >> 4) * 4 + r;
            if (m >= M) continue;
            #pragma unroll
            for (int j = 0; j < 4; ++j) {
                int n = wn + j * 16 + lr;
                C[(long)m * 128 + n] = acc[i][j][r];
            }
        }
}

// ---------------------------------------------------------------------------
__global__ __launch_bounds__(256) void split_kernel(
    const float* __restrict__ src, ushort_t* __restrict__ hi,
    ushort_t* __restrict__ lo, int n)
{
    int i = blockIdx.x * blockDim.x + threadIdx.x;
    if (i >= n) return;
    float x = src[i];
    unsigned short h = f2b(x);
    hi[i] = h;
    lo[i] = f2b(x - b2f(h));
}

// ---------------------------------------------------------------------------
// dist_W transpose: dW [NCONV][3*128][20]  ->  dWt [NCONV][3][5][128][4]
// so edge_aggr lanes can preload their 60 coefficients with 15 coalesced
// float4 loads (once per block).
// ---------------------------------------------------------------------------
__global__ __launch_bounds__(256) void transpose_dw_kernel(
    const float* __restrict__ dW, float* __restrict__ dWt, int total)
{
    int idx = blockIdx.x * blockDim.x + threadIdx.x;
    if (idx >= total) return;
    int kk = idx & 3;
    int f  = (idx >> 2) & 127;
    int k4 = (idx >> 9) % 5;
    int c  = (idx / (4 * 128 * 5)) % 3;
    int l  = idx / (4 * 128 * 5 * 3);
    int k  = k4 * 4 + kk;
    dWt[idx] = dW[((long)(l * 3 + c) * 128 + f) * NRBF + k];
}

// ---------------------------------------------------------------------------
// CSR build
// ---------------------------------------------------------------------------
__global__ __launch_bounds__(256) void hist_kernel(
    const int* __restrict__ nbr, int* __restrict__ deg, int Ed)
{
    int e = blockIdx.x * blockDim.x + threadIdx.x;
    if (e >= Ed) return;
    int E = Ed >> 1;
    int i = (e < E) ? nbr[2 * e] : nbr[2 * (e - E) + 1];
    atomicAdd(&deg[i], 1);
}

__device__ inline int wave_incl_scan(int x, int lane)
{
    #pragma unroll
    for (int s = 1; s < 64; s <<= 1) {
        int y = __shfl_up(x, s, 64);
        if (lane >= s) x += y;
    }
    return x;
}

__global__ __launch_bounds__(1024) void scan_kernel(
    const int* __restrict__ deg, int* __restrict__ off,
    int* __restrict__ cursor, int N)
{
    __shared__ int wsum[16];
    __shared__ int carry_s;
    const int t = threadIdx.x;
    const int lane = t & 63;
    const int w = t >> 6;
    if (t == 0) { carry_s = 0; off[0] = 0; }
    __syncthreads();
    for (int base = 0; base < N; base += 1024) {
        int i = base + t;
        int x = (i < N) ? deg[i] : 0;
        int sc = wave_incl_scan(x, lane);
        if (lane == 63) wsum[w] = sc;
        __syncthreads();
        if (w == 0) {
            int v = (lane < 16) ? wsum[lane] : 0;
            int vs = wave_incl_scan(v, lane);
            if (lane < 16) wsum[lane] = vs;
        }
        __syncthreads();
        int waveoff = (w > 0) ? wsum[w - 1] : 0;
        int inc = sc + waveoff + carry_s;
        if (i < N) { off[i + 1] = inc; cursor[i] = inc - x; }
        __syncthreads();
        if (t == 1023) carry_s = inc;
        __syncthreads();
    }
}

__global__ __launch_bounds__(256) void scatter_geom_kernel(
    const int* __restrict__ nbr, const float* __restrict__ xyz,
    int* __restrict__ cursor, int* __restrict__ csr_j,
    float* __restrict__ csr_geo, float* __restrict__ csr_rbfe, int Ed)
{
    int e = blockIdx.x * blockDim.x + threadIdx.x;
    if (e >= Ed) return;
    int E = Ed >> 1;
    int i, j;
    if (e < E) { i = nbr[2 * e];         j = nbr[2 * e + 1]; }
    else       { int u = e - E; i = nbr[2 * u + 1]; j = nbr[2 * u]; }

    int p = atomicAdd(&cursor[i], 1);
    csr_j[p] = j;

    float rx = xyz[3 * j + 0] - xyz[3 * i + 0];
    float ry = xyz[3 * j + 1] - xyz[3 * i + 1];
    float rz = xyz[3 * j + 2] - xyz[3 * i + 2];
    float d   = sqrtf(rx * rx + ry * ry + rz * rz);
    float inv = 1.f / d;
    float ev = (d < 20.f) ? 0.5f * (__cosf(PI_F * d / 20.f) + 1.f) : 0.f;
    ((float4*)csr_geo)[p] = make_float4(rx * inv, ry * inv, rz * inv, ev);
    float base = PI_F * d / 20.f;
    #pragma unroll
    for (int k = 0; k < NRBF; ++k)
        csr_rbfe[(long)p * NRBF + k] = ev * __sinf((float)(k + 1) * base) * inv;
}

// ---------------------------------------------------------------------------
// Edge aggregation v5 — concurrency-first:
//  - ONE uint4 (16B) gather per edge-lane: {ph0|ph1, ph2|vh0, vh1|vh2, vl8x3}
//  - 4-wide x depth-2 batch pipeline -> 8 gathers in flight per wave
//  - blocks own contiguous NODE ranges and stream their contiguous EDGE
//    range; accumulator flush at node boundaries -> pipeline never drains
//  - cw coefficients pinned in VGPRs via asm keepalive (v4's VGPR=52 showed
//    the compiler rematerializes the loads per edge otherwise)
// ---------------------------------------------------------------------------
__global__ __launch_bounds__(128) void edge_aggr_kernel(
    const int* __restrict__ off, const int* __restrict__ csr_j,
    const float* __restrict__ csr_geo, const float* __restrict__ csr_rbfe,
    const float* __restrict__ dWt, const float* __restrict__ distb,
    const uint4* __restrict__ cg, const float* __restrict__ vold,
    float* __restrict__ s, float* __restrict__ vnew,
    ushort_t* __restrict__ vnh, ushort_t* __restrict__ vnl, int N, int SP)
{
    const int f = threadIdx.x;   // 0..127

    // 60 dist coefficients for this lane's f, pinned in registers
    float4 cw[3][5];
    #pragma unroll
    for (int c = 0; c < 3; ++c)
        #pragma unroll
        for (int k4 = 0; k4 < 5; ++k4) {
            cw[c][k4] = *(const float4*)(dWt + (long)((c * 5 + k4) * 512 + f * 4));
            asm volatile("" : "+v"(cw[c][k4].x), "+v"(cw[c][k4].y),
                              "+v"(cw[c][k4].z), "+v"(cw[c][k4].w));
        }
    const float bb0 = distb[f], bb1 = distb[128 + f], bb2 = distb[256 + f];

    const float4* __restrict__ geo4 = (const float4*)csr_geo;
    const float4* __restrict__ v4p  = (const float4*)vold;

    // contiguous node range for this block
    const int per = (N + gridDim.x - 1) / gridDim.x;
    int node = blockIdx.x * per;
    int n1 = node + per; if (n1 > N) n1 = N;
    if (node >= n1) return;

    const int e0 = off[node];
    const int e1 = off[n1];
    int nodeEnd = off[node + 1];

    float ssum = 0.f, v0 = 0.f, v1 = 0.f, v2 = 0.f;

    auto flushNode = [&](int nd) {
        long iv = (long)nd * FEAT + f;
        s[iv] += ssum;
        float4 vc = v4p[iv];
        float m0 = vc.x + v0, m1 = vc.y + v1, m2 = vc.z + v2;
        ((float4*)vnew)[iv] = make_float4(m0, m1, m2, 0.f);
        unsigned short h0 = f2b(m0), h1 = f2b(m1), h2 = f2b(m2);
        vnh[iv]          = h0;  vnl[iv]          = f2b(m0 - b2f(h0));
        vnh[SP + iv]     = h1;  vnl[SP + iv]     = f2b(m1 - b2f(h1));
        vnh[2 * SP + iv] = h2;  vnl[2 * SP + iv] = f2b(m2 - b2f(h2));
        ssum = v0 = v1 = v2 = 0.f;
    };

    auto fetch = [&](int pp) -> uint4 {
        if (pp < e1) {
            int j = __builtin_amdgcn_readfirstlane(csr_j[pp]);
            return cg[(long)j * 128 + f];
        }
        return make_uint4(0u, 0u, 0u, 0u);
    };

    auto procEdge = [&](int p, uint4 g) {
        while (p >= nodeEnd) {            // node boundary (wave-uniform)
            flushNode(node); ++node;
            nodeEnd = off[node + 1];
        }
        int pu = __builtin_amdgcn_readfirstlane(p);
        float4 ge = geo4[pu];                     // {ux,uy,uz,env} uniform
        const float4* rb4 = (const float4*)(csr_rbfe + (long)pu * NRBF);
        float w0 = ge.w * bb0, w1 = ge.w * bb1, w2 = ge.w * bb2;
        #pragma unroll
        for (int k4 = 0; k4 < 5; ++k4) {
            float4 r = rb4[k4];                   // uniform
            w0 += r.x * cw[0][k4].x + r.y * cw[0][k4].y
                + r.z * cw[0][k4].z + r.w * cw[0][k4].w;
            w1 += r.x * cw[1][k4].x + r.y * cw[1][k4].y
                + r.z * cw[1][k4].z + r.w * cw[1][k4].w;
            w2 += r.x * cw[2][k4].x + r.y * cw[2][k4].y
                + r.z * cw[2][k4].z + r.w * cw[2][k4].w;
        }
        float i0 = u2f(g.x << 16)          * w0;  // b2f(ph0)
        float i1 = u2f(g.x & 0xffff0000u)  * w1;  // b2f(ph1)
        float i2 = u2f(g.y << 16)          * w2;  // b2f(ph2)
        // v[j]: top-24-bit fp32 reconstruction
        float vx = u2f((g.y & 0xffff0000u) | ((g.w & 0xffu) << 8));
        float vy = u2f(((g.z & 0xffffu) << 16) | (((g.w >> 8) & 0xffu) << 8));
        float vz = u2f((g.z & 0xffff0000u) | (((g.w >> 16) & 0xffu) << 8));
        ssum += i1;
        v0 += i2 * ge.x + i0 * vx;
        v1 += i2 * ge.y + i0 * vy;
        v2 += i2 * ge.z + i0 * vz;
    };

    // 4-wide, depth-2 pipeline: 8 gathers in flight
    uint4 nb0 = fetch(e0), nb1 = fetch(e0 + 1),
          nb2 = fetch(e0 + 2), nb3 = fetch(e0 + 3);

    for (int eb = e0; eb < e1; eb += 4) {
        uint4 c0 = nb0, c1 = nb1, c2 = nb2, c3 = nb3;
        nb0 = fetch(eb + 4); nb1 = fetch(eb + 5);
        nb2 = fetch(eb + 6); nb3 = fetch(eb + 7);
        procEdge(eb, c0);
        if (eb + 1 < e1) procEdge(eb + 1, c1);
        if (eb + 2 < e1) procEdge(eb + 2, c2);
        if (eb + 3 < e1) procEdge(eb + 3, c3);
    }

    flushNode(node); ++node;
    while (node < n1) { flushNode(node); ++node; }   // trailing 0-degree nodes
}

// ---------------------------------------------------------------------------
// Elementwise kernels
// ---------------------------------------------------------------------------
__global__ __launch_bounds__(256) void init_s_kernel(
    const float* __restrict__ cg_s, float* __restrict__ s,
    float* __restrict__ vA, uint4* __restrict__ cg, int nS, int nV)
{
    int idx = blockIdx.x * blockDim.x + threadIdx.x;
    if (idx < nS) {
        s[idx] = cg_s[idx];
        cg[idx] = make_uint4(0u, 0u, 0u, 0u);
    }
    if (idx < nV) vA[idx] = 0.f;
}

// final: if outv != null, v result goes interleaved to outv (and v not written)
// v / vnew are PACKED float4 [idx][4]; also emits 24-bit v into the merged
// cg record (ushort slot 3 + uints 2,3) for the next layer's edge gathers.
__global__ __launch_bounds__(256) void update_sv_kernel(
    float* __restrict__ s, float* __restrict__ v,
    const float* __restrict__ uv, const float* __restrict__ vv,
    const float* __restrict__ a, float* __restrict__ outv,
    ushort_t* __restrict__ cgu, int SP)
{
    int idx = blockIdx.x * blockDim.x + threadIdx.x;
    if (idx >= SP) return;
    int n = idx >> 7, g = idx & 127;
    float u0 = uv[idx], u1 = uv[SP + idx], u2 = uv[2 * SP + idx];
    float w0 = vv[idx], w1 = vv[SP + idx], w2 = vv[2 * SP + idx];
    long ab = (long)n * 384;
    float dot = u0 * w0 + u1 * w1 + u2 * w2;
    s[idx] += dot * a[ab + 128 + g] + a[ab + 256 + g];
    float g0 = a[ab + g];
    float4 xv = ((const float4*)v)[idx];
    float x0 = xv.x + u0 * g0;
    float x1 = xv.y + u1 * g0;
    float x2 = xv.z + u2 * g0;
    if (outv) {
        outv[(long)idx * 3 + 0] = x0;
        outv[(long)idx * 3 + 1] = x1;
        outv[(long)idx * 3 + 2] = x2;
    } else {
        ((float4*)v)[idx] = make_float4(x0, x1, x2, 0.f);
        unsigned int u0b = f2u(x0), u1b = f2u(x1), u2b = f2u(x2);
        cgu[(long)idx * 8 + 3] = (ushort_t)(u0b >> 16);          // vh0
        unsigned int* cg32 = (unsigned int*)cgu;
        cg32[(long)idx * 4 + 2] = (u1b >> 16) | (u2b & 0xffff0000u);   // vh1|vh2
        cg32[(long)idx * 4 + 3] = ((u0b >> 8) & 0xffu) |
                                  (((u1b >> 8) & 0xffu) << 8) |
                                  (((u2b >> 8) & 0xffu) << 16);        // vl8x3
    }
}

// ---------------------------------------------------------------------------
extern "C" void kernel_launch(void* const* d_in, const int* in_sizes, int n_in,
                              void* d_out, int out_size, void* d_ws, size_t ws_size,
                              hipStream_t stream)
{
    const float* xyz     = (const float*)d_in[0];
    const int*   nbr     = (const int*)  d_in[1];
    const float* cg_s    = (const float*)d_in[2];
    const float* msg_W1  = (const float*)d_in[3];
    const float* msg_b1  = (const float*)d_in[4];
    const float* msg_W2  = (const float*)d_in[5];
    const float* msg_b2  = (const float*)d_in[6];
    const float* dist_W  = (const float*)d_in[7];
    const float* dist_b  = (const float*)d_in[8];
    const float* upd_U   = (const float*)d_in[9];
    const float* upd_V   = (const float*)d_in[10];
    const float* upd_sW1 = (const float*)d_in[11];
    const float* upd_sb1 = (const float*)d_in[12];
    const float* upd_sW2 = (const float*)d_in[13];
    const float* upd_sb2 = (const float*)d_in[14];

    const int E  = in_sizes[1] / 2;
    const int Ed = 2 * E;
    const int N  = in_sizes[2] / FEAT;
    const int SP = N * FEAT;

    float* s    = (float*)d_out;
    float* outv = (float*)d_out + (long)SP;

    // workspace carve-up
    float* w = (float*)d_ws;
    size_t off_ = 0;
    auto alloc = [&](size_t nelem) {
        float* p = w + off_;
        off_ += (nelem + 255) & ~(size_t)255;
        return p;
    };
    auto allocb = [&](size_t nelem) {
        return (ushort_t*)alloc((nelem + 1) / 2);
    };
    int*   deg      = (int*)alloc((size_t)N);
    int*   off      = (int*)alloc((size_t)N + 1);
    int*   cursor   = (int*)alloc((size_t)N);
    int*   csr_j    = (int*)alloc((size_t)Ed);
    float* csr_geo  = alloc((size_t)Ed * 4);
    float* csr_rbfe = alloc((size_t)Ed * NRBF);
    float* a_buf    = alloc((size_t)N * 384);
    float* u_v      = alloc((size_t)3 * SP);
    float* v_v      = alloc((size_t)3 * SP);
    float* vA       = alloc((size_t)4 * SP);   // packed [idx][4] fp32
    float* vB       = alloc((size_t)4 * SP);   // packed [idx][4] fp32
    float* dWt      = alloc((size_t)NCONV * 3 * NRBF * FEAT);
    ushort_t* cgbuf = allocb((size_t)N * 1024); // merged 16B records [node][128]
    ushort_t* vnh   = allocb((size_t)3 * SP);
    ushort_t* vnl   = allocb((size_t)3 * SP);
    const int n1 = NCONV * FEAT * FEAT;
    const int n2 = NCONV * 3 * FEAT * FEAT;
    const int n3 = NCONV * FEAT * 2 * FEAT;
    ushort_t* w1h  = allocb((size_t)n1);
    ushort_t* w1l  = allocb((size_t)n1);
    ushort_t* w2h  = allocb((size_t)n2);
    ushort_t* w2l  = allocb((size_t)n2);
    ushort_t* uh   = allocb((size_t)n1);
    ushort_t* ul   = allocb((size_t)n1);
    ushort_t* vh   = allocb((size_t)n1);
    ushort_t* vl   = allocb((size_t)n1);
    ushort_t* sw1h = allocb((size_t)n3);
    ushort_t* sw1l = allocb((size_t)n3);
    ushort_t* sw2h = allocb((size_t)n2);
    ushort_t* sw2l = allocb((size_t)n2);
    (void)ws_size; (void)n_in; (void)out_size;

    // weight split (once per launch)
    split_kernel<<<(n1 + 255) / 256, 256, 0, stream>>>(msg_W1, w1h, w1l, n1);
    split_kernel<<<(n2 + 255) / 256, 256, 0, stream>>>(msg_W2, w2h, w2l, n2);
    split_kernel<<<(n1 + 255) / 256, 256, 0, stream>>>(upd_U, uh, ul, n1);
    split_kernel<<<(n1 + 255) / 256, 256, 0, stream>>>(upd_V, vh, vl, n1);
    split_kernel<<<(n3 + 255) / 256, 256, 0, stream>>>(upd_sW1, sw1h, sw1l, n3);
    split_kernel<<<(n2 + 255) / 256, 256, 0, stream>>>(upd_sW2, sw2h, sw2l, n2);

    // dist_W transpose (once per launch, all layers)
    {
        int total = NCONV * 3 * NRBF * FEAT;
        transpose_dw_kernel<<<(total + 255) / 256, 256, 0, stream>>>(
            dist_W, dWt, total);
    }

    // init s <- cg_s, vA <- 0, cg records <- 0
    {
        int n = 4 * SP;
        init_s_kernel<<<(n + 255) / 256, 256, 0, stream>>>(
            cg_s, s, vA, (uint4*)cgbuf, SP, n);
    }

    // CSR build (once per launch)
    hipMemsetAsync(deg, 0, (size_t)N * sizeof(int), stream);
    hist_kernel<<<(Ed + 255) / 256, 256, 0, stream>>>(nbr, deg, Ed);
    scan_kernel<<<1, 1024, 0, stream>>>(deg, off, cursor, N);
    scatter_geom_kernel<<<(Ed + 255) / 256, 256, 0, stream>>>(
        nbr, xyz, cursor, csr_j, csr_geo, csr_rbfe, Ed);

    float* vold = vA;
    float* vnew = vB;
    dim3 gM((N + 127) / 128, 1);
    dim3 gUV((3 * N + 127) / 128, 2);
    int edgeGrid = 4096;
    if (edgeGrid > N) edgeGrid = N;

    for (int l = 0; l < NCONV; ++l) {
        const float* b1  = msg_b1  + (long)l * FEAT;
        const float* b2  = msg_b2  + (long)l * 3 * FEAT;
        const float* db  = dist_b  + (long)l * 3 * FEAT;
        const float* sb1 = upd_sb1 + (long)l * FEAT;
        const float* sb2 = upd_sb2 + (long)l * 3 * FEAT;
        const long o1 = (long)l * FEAT * FEAT;
        const long o2 = (long)l * 3 * FEAT * FEAT;
        const long o3 = (long)l * FEAT * 2 * FEAT;

        // fused phi-MLP: s -> (h in LDS) -> cg phi slots (packed bf16 hi)
        mlp_fused_kernel<<<gM, 256, 0, stream>>>(
            s, nullptr, w1h + o1, w1l + o1, b1, w2h + o2, w2l + o2, b2,
            cgbuf, nullptr, N, FEAT, SP);

        // atomic-free message aggregation (v5)
        edge_aggr_kernel<<<edgeGrid, 128, 0, stream>>>(
            off, csr_j, csr_geo, csr_rbfe, dWt + (long)l * 3 * NRBF * FEAT, db,
            (const uint4*)cgbuf, vold, s, vnew, vnh, vnl, N, SP);

        // u_v / v_v in one dispatch (y=0 -> U, y=1 -> V)
        gemm_ps_kernel<<<gUV, 256, 0, stream>>>(
            vnh, vnl, uh + o1, ul + o1, vh + o1, vl + o1,
            u_v, v_v, 3 * N, FEAT);

        // fused gate-MLP: [s | norm(v_v)] -> (h in LDS) -> a_buf (fp32)
        mlp_fused_kernel<<<gM, 256, 0, stream>>>(
            s, v_v, sw1h + o3, sw1l + o3, sb1, sw2h + o2, sw2l + o2, sb2,
            nullptr, a_buf, N, 2 * FEAT, SP);

        // final update; last layer writes v interleaved straight to output
        float* ov = (l == NCONV - 1) ? outv : nullptr;
        update_sv_kernel<<<(SP + 255) / 256, 256, 0, stream>>>(
            s, vnew, u_v, v_v, a_buf, ov, cgbuf, SP);

        float* tmp = vold; vold = vnew; vnew = tmp;
    }
}

// Round 5
// 1031.385 us; speedup vs baseline: 1.1013x; 1.1013x over previous
//
#include <hip/hip_runtime.h>
#include <math.h>

#define FEAT 128
#define NRBF 20
#define NCONV 3
#define PI_F 3.14159265358979323846f

typedef __attribute__((ext_vector_type(8))) short short8;
typedef __attribute__((ext_vector_type(4))) float floatx4;
typedef unsigned short ushort_t;

__device__ inline float b2f(unsigned short u) {
    union { unsigned int i; float f; } c; c.i = ((unsigned int)u) << 16; return c.f;
}
__device__ inline unsigned short f2b(float x) {
    union { float f; unsigned int i; } c; c.f = x;
    unsigned int u = c.i;
    return (unsigned short)((u + 0x7fffu + ((u >> 16) & 1u)) >> 16);
}

// ---------------------------------------------------------------------------
// Fused 2-layer MLP: out[M,384] = silu(A1 @ W1^T + b1) @ W2^T + b2
// A1 = s[M,128] (phi mode) or [s | norm(vv)] [M,256] (gate mode, vv != null).
// Hidden h (128-wide = one K-tile) lives in LDS hi/lo; never touches HBM.
// Split-precision: acc += Ah*Wh + Ah*Wl + Al*Wh throughout.
// out: bf16-hi (out_b, phi mode) or fp32 (out_f, gate mode).
// 128-row m-tile, 256 thr = 4 waves, per-wave 64x64 via 4x4 16x16x32 MFMA.
// LDS: 4x10KB staging + 2x34.8KB h = 110 KB -> 1 block/CU.
// ---------------------------------------------------------------------------
__global__ __launch_bounds__(256) void mlp_fused_kernel(
    const float* __restrict__ s, const float* __restrict__ vv,
    const ushort_t* __restrict__ W1h, const ushort_t* __restrict__ W1l,
    const float* __restrict__ b1,
    const ushort_t* __restrict__ W2h, const ushort_t* __restrict__ W2l,
    const float* __restrict__ b2,
    ushort_t* __restrict__ out_b, float* __restrict__ out_f,
    int M, int K1, int SP)
{
    __shared__ __align__(16) ushort_t Ah[128 * 40];
    __shared__ __align__(16) ushort_t Al[128 * 40];
    __shared__ __align__(16) ushort_t Wh[128 * 40];
    __shared__ __align__(16) ushort_t Wl[128 * 40];
    __shared__ __align__(16) ushort_t Hh[128 * 136];
    __shared__ __align__(16) ushort_t Hl[128 * 136];

    const int t    = threadIdx.x;
    const int m0   = blockIdx.x * 128;
    const int wv   = t >> 6;
    const int lane = t & 63;
    const int wm   = (wv >> 1) * 64;
    const int wn   = (wv & 1) * 64;
    const int lr   = lane & 15;
    const int lk   = (lane >> 4) * 8;
    const int quad = lane >> 4;
    const int arow = t >> 3;          // 0..31, 4 passes of 32 rows
    const int acol = (t & 7) * 4;     // fp32 x4
    const int wrow = t >> 2;          // 0..63, 2 passes of 64 rows
    const int wcol = (t & 3) * 8;     // ushort x8

    floatx4 acc[4][4] = {};

    // ---- stage 1: h = silu(A1 @ W1^T + b1) ----
    for (int k0 = 0; k0 < K1; k0 += 32) {
        #pragma unroll
        for (int h = 0; h < 4; ++h) {
            int r = arow + h * 32;
            int m = m0 + r; if (m >= M) m = M - 1;   // clamp tail
            float xs[4];
            if (k0 < 128) {
                float4 av = *(const float4*)(s + (long)m * 128 + k0 + acol);
                xs[0] = av.x; xs[1] = av.y; xs[2] = av.z; xs[3] = av.w;
            } else {
                long base = (long)m * 128 + (k0 - 128 + acol);
                float4 a0 = *(const float4*)(vv + base);
                float4 a1 = *(const float4*)(vv + (long)SP + base);
                float4 a2 = *(const float4*)(vv + 2 * (long)SP + base);
                xs[0] = sqrtf(a0.x * a0.x + a1.x * a1.x + a2.x * a2.x);
                xs[1] = sqrtf(a0.y * a0.y + a1.y * a1.y + a2.y * a2.y);
                xs[2] = sqrtf(a0.z * a0.z + a1.z * a1.z + a2.z * a2.z);
                xs[3] = sqrtf(a0.w * a0.w + a1.w * a1.w + a2.w * a2.w);
            }
            unsigned short hh[4], ll[4];
            #pragma unroll
            for (int q = 0; q < 4; ++q) {
                hh[q] = f2b(xs[q]);
                ll[q] = f2b(xs[q] - b2f(hh[q]));
            }
            *(ushort4*)(&Ah[r * 40 + acol]) = make_ushort4(hh[0], hh[1], hh[2], hh[3]);
            *(ushort4*)(&Al[r * 40 + acol]) = make_ushort4(ll[0], ll[1], ll[2], ll[3]);
        }
        #pragma unroll
        for (int h = 0; h < 2; ++h) {
            int r = wrow + h * 64;
            *(uint4*)(&Wh[r * 40 + wcol]) =
                *(const uint4*)(W1h + (long)r * K1 + k0 + wcol);
            *(uint4*)(&Wl[r * 40 + wcol]) =
                *(const uint4*)(W1l + (long)r * K1 + k0 + wcol);
        }
        __syncthreads();
        short8 af[4], alf[4], wf[4], wlf[4];
        #pragma unroll
        for (int i = 0; i < 4; ++i) {
            af[i]  = *(const short8*)(&Ah[(wm + i * 16 + lr) * 40 + lk]);
            alf[i] = *(const short8*)(&Al[(wm + i * 16 + lr) * 40 + lk]);
            wf[i]  = *(const short8*)(&Wh[(wn + i * 16 + lr) * 40 + lk]);
            wlf[i] = *(const short8*)(&Wl[(wn + i * 16 + lr) * 40 + lk]);
        }
        #pragma unroll
        for (int i = 0; i < 4; ++i)
            #pragma unroll
            for (int j = 0; j < 4; ++j) {
                acc[i][j] = __builtin_amdgcn_mfma_f32_16x16x32_bf16(
                    af[i], wf[j], acc[i][j], 0, 0, 0);
                acc[i][j] = __builtin_amdgcn_mfma_f32_16x16x32_bf16(
                    af[i], wlf[j], acc[i][j], 0, 0, 0);
                acc[i][j] = __builtin_amdgcn_mfma_f32_16x16x32_bf16(
                    alf[i], wf[j], acc[i][j], 0, 0, 0);
            }
        __syncthreads();
    }

    // stage-1 epilogue -> h in LDS (hi/lo), C/D layout col=lane&15, row=quad*4+r
    #pragma unroll
    for (int i = 0; i < 4; ++i)
        #pragma unroll
        for (int r = 0; r < 4; ++r) {
            int mrow = wm + i * 16 + quad * 4 + r;
            #pragma unroll
            for (int j = 0; j < 4; ++j) {
                int kcol = wn + j * 16 + lr;
                float x = acc[i][j][r] + b1[kcol];
                x *= 1.f / (1.f + __expf(-x));
                unsigned short hh = f2b(x);
                Hh[mrow * 136 + kcol] = hh;
                Hl[mrow * 136 + kcol] = f2b(x - b2f(hh));
            }
        }

    // ---- stage 2: out = h @ W2^T + b2, 3 n-tiles of 128 ----
    for (int nt = 0; nt < 3; ++nt) {
        #pragma unroll
        for (int i = 0; i < 4; ++i)
            #pragma unroll
            for (int j = 0; j < 4; ++j)
                #pragma unroll
                for (int q = 0; q < 4; ++q) acc[i][j][q] = 0.f;
        for (int k0 = 0; k0 < 128; k0 += 32) {
            __syncthreads();   // guard Wh/Wl overwrite (and H writes on 1st pass)
            #pragma unroll
            for (int h = 0; h < 2; ++h) {
                int r = wrow + h * 64;
                long wo = (long)(nt * 128 + r) * 128;
                *(uint4*)(&Wh[r * 40 + wcol]) = *(const uint4*)(W2h + wo + k0 + wcol);
                *(uint4*)(&Wl[r * 40 + wcol]) = *(const uint4*)(W2l + wo + k0 + wcol);
            }
            __syncthreads();
            short8 af[4], alf[4], wf[4], wlf[4];
            #pragma unroll
            for (int i = 0; i < 4; ++i) {
                af[i]  = *(const short8*)(&Hh[(wm + i * 16 + lr) * 136 + k0 + lk]);
                alf[i] = *(const short8*)(&Hl[(wm + i * 16 + lr) * 136 + k0 + lk]);
                wf[i]  = *(const short8*)(&Wh[(wn + i * 16 + lr) * 40 + lk]);
                wlf[i] = *(const short8*)(&Wl[(wn + i * 16 + lr) * 40 + lk]);
            }
            #pragma unroll
            for (int i = 0; i < 4; ++i)
                #pragma unroll
                for (int j = 0; j < 4; ++j) {
                    acc[i][j] = __builtin_amdgcn_mfma_f32_16x16x32_bf16(
                        af[i], wf[j], acc[i][j], 0, 0, 0);
                    acc[i][j] = __builtin_amdgcn_mfma_f32_16x16x32_bf16(
                        af[i], wlf[j], acc[i][j], 0, 0, 0);
                    acc[i][j] = __builtin_amdgcn_mfma_f32_16x16x32_bf16(
                        alf[i], wf[j], acc[i][j], 0, 0, 0);
                }
        }
        #pragma unroll
        for (int i = 0; i < 4; ++i)
            #pragma unroll
            for (int r = 0; r < 4; ++r) {
                int m = m0 + wm + i * 16 + quad * 4 + r;
                if (m >= M) continue;
                #pragma unroll
                for (int j = 0; j < 4; ++j) {
                    int n = nt * 128 + wn + j * 16 + lr;
                    float x = acc[i][j][r] + b2[n];
                    if (out_b) out_b[(long)m * 384 + n] = f2b(x);
                    else       out_f[(long)m * 384 + n] = x;
                }
            }
    }
}

// ---------------------------------------------------------------------------
// Pre-split MFMA GEMM (UV only): dual weights, fp32 C0/C1 routing by n-tile.
// ---------------------------------------------------------------------------
__global__ __launch_bounds__(256) void gemm_ps_kernel(
    const ushort_t* __restrict__ Ahg, const ushort_t* __restrict__ Alg,
    const ushort_t* __restrict__ Whi, const ushort_t* __restrict__ Wlo,
    const ushort_t* __restrict__ W2h, const ushort_t* __restrict__ W2l,
    float* __restrict__ C0, float* __restrict__ C1,
    int M, int K)
{
    __shared__ __align__(16) ushort_t Ah[128 * 40];
    __shared__ __align__(16) ushort_t Al[128 * 40];
    __shared__ __align__(16) ushort_t Wh[128 * 40];
    __shared__ __align__(16) ushort_t Wl[128 * 40];
    const int t    = threadIdx.x;
    const int m0   = blockIdx.x * 128;
    const int nt   = blockIdx.y;          // 0 -> U/C0, 1 -> V/C1
    const int wv   = t >> 6;
    const int lane = t & 63;
    const int wm   = (wv >> 1) * 64;
    const int wn   = (wv & 1) * 64;
    const int lr   = lane & 15;
    const int lk   = (lane >> 4) * 8;
    const int srow = t >> 2;
    const int scol = (t & 3) * 8;
    const ushort_t* Wsh = nt ? W2h : Whi;
    const ushort_t* Wsl = nt ? W2l : Wlo;

    floatx4 acc[4][4] = {};

    for (int k0 = 0; k0 < K; k0 += 32) {
        #pragma unroll
        for (int h = 0; h < 2; ++h) {
            int r = srow + h * 64;
            int m = m0 + r; if (m >= M) m = M - 1;
            *(uint4*)(&Ah[r * 40 + scol]) =
                *(const uint4*)(Ahg + (long)m * K + k0 + scol);
            *(uint4*)(&Al[r * 40 + scol]) =
                *(const uint4*)(Alg + (long)m * K + k0 + scol);
            *(uint4*)(&Wh[r * 40 + scol]) =
                *(const uint4*)(Wsh + (long)r * K + k0 + scol);
            *(uint4*)(&Wl[r * 40 + scol]) =
                *(const uint4*)(Wsl + (long)r * K + k0 + scol);
        }
        __syncthreads();
        short8 ah[4], al[4], wh[4], wl[4];
        #pragma unroll
        for (int i = 0; i < 4; ++i) {
            ah[i] = *(const short8*)(&Ah[(wm + i * 16 + lr) * 40 + lk]);
            al[i] = *(const short8*)(&Al[(wm + i * 16 + lr) * 40 + lk]);
            wh[i] = *(const short8*)(&Wh[(wn + i * 16 + lr) * 40 + lk]);
            wl[i] = *(const short8*)(&Wl[(wn + i * 16 + lr) * 40 + lk]);
        }
        #pragma unroll
        for (int i = 0; i < 4; ++i)
            #pragma unroll
            for (int j = 0; j < 4; ++j) {
                acc[i][j] = __builtin_amdgcn_mfma_f32_16x16x32_bf16(
                    ah[i], wh[j], acc[i][j], 0, 0, 0);
                acc[i][j] = __builtin_amdgcn_mfma_f32_16x16x32_bf16(
                    ah[i], wl[j], acc[i][j], 0, 0, 0);
                acc[i][j] = __builtin_amdgcn_mfma_f32_16x16x32_bf16(
                    al[i], wh[j], acc[i][j], 0, 0, 0);
            }
        __syncthreads();
    }

    float* C = nt ? C1 : C0;
    #pragma unroll
    for (int i = 0; i < 4; ++i)
        #pragma unroll
        for (int r = 0; r < 4; ++r) {
            int m = m0 + wm + i * 16 + (lane >> 4) * 4 + r;
            if (m >= M) continue;
            #pragma unroll
            for (int j = 0; j < 4; ++j) {
                int n = wn + j * 16 + lr;
                C[(long)m * 128 + n] = acc[i][j][r];
            }
        }
}

// ---------------------------------------------------------------------------
__global__ __launch_bounds__(256) void split_kernel(
    const float* __restrict__ src, ushort_t* __restrict__ hi,
    ushort_t* __restrict__ lo, int n)
{
    int i = blockIdx.x * blockDim.x + threadIdx.x;
    if (i >= n) return;
    float x = src[i];
    unsigned short h = f2b(x);
    hi[i] = h;
    lo[i] = f2b(x - b2f(h));
}

// ---------------------------------------------------------------------------
// CSR build
// ---------------------------------------------------------------------------
__global__ __launch_bounds__(256) void hist_kernel(
    const int* __restrict__ nbr, int* __restrict__ deg, int Ed)
{
    int e = blockIdx.x * blockDim.x + threadIdx.x;
    if (e >= Ed) return;
    int E = Ed >> 1;
    int i = (e < E) ? nbr[2 * e] : nbr[2 * (e - E) + 1];
    atomicAdd(&deg[i], 1);
}

__device__ inline int wave_incl_scan(int x, int lane)
{
    #pragma unroll
    for (int s = 1; s < 64; s <<= 1) {
        int y = __shfl_up(x, s, 64);
        if (lane >= s) x += y;
    }
    return x;
}

__global__ __launch_bounds__(1024) void scan_kernel(
    const int* __restrict__ deg, int* __restrict__ off,
    int* __restrict__ cursor, int N)
{
    __shared__ int wsum[16];
    __shared__ int carry_s;
    const int t = threadIdx.x;
    const int lane = t & 63;
    const int w = t >> 6;
    if (t == 0) { carry_s = 0; off[0] = 0; }
    __syncthreads();
    for (int base = 0; base < N; base += 1024) {
        int i = base + t;
        int x = (i < N) ? deg[i] : 0;
        int sc = wave_incl_scan(x, lane);
        if (lane == 63) wsum[w] = sc;
        __syncthreads();
        if (w == 0) {
            int v = (lane < 16) ? wsum[lane] : 0;
            int vs = wave_incl_scan(v, lane);
            if (lane < 16) wsum[lane] = vs;
        }
        __syncthreads();
        int waveoff = (w > 0) ? wsum[w - 1] : 0;
        int inc = sc + waveoff + carry_s;
        if (i < N) { off[i + 1] = inc; cursor[i] = inc - x; }
        __syncthreads();
        if (t == 1023) carry_s = inc;
        __syncthreads();
    }
}

__global__ __launch_bounds__(256) void scatter_geom_kernel(
    const int* __restrict__ nbr, const float* __restrict__ xyz,
    int* __restrict__ cursor, int* __restrict__ csr_j,
    float* __restrict__ csr_env, float* __restrict__ csr_unit,
    float* __restrict__ csr_rbfe, int Ed)
{
    int e = blockIdx.x * blockDim.x + threadIdx.x;
    if (e >= Ed) return;
    int E = Ed >> 1;
    int i, j;
    if (e < E) { i = nbr[2 * e];         j = nbr[2 * e + 1]; }
    else       { int u = e - E; i = nbr[2 * u + 1]; j = nbr[2 * u]; }

    int p = atomicAdd(&cursor[i], 1);
    csr_j[p] = j;

    float rx = xyz[3 * j + 0] - xyz[3 * i + 0];
    float ry = xyz[3 * j + 1] - xyz[3 * i + 1];
    float rz = xyz[3 * j + 2] - xyz[3 * i + 2];
    float d   = sqrtf(rx * rx + ry * ry + rz * rz);
    float inv = 1.f / d;
    csr_unit[3 * p + 0] = rx * inv;
    csr_unit[3 * p + 1] = ry * inv;
    csr_unit[3 * p + 2] = rz * inv;
    float ev = (d < 20.f) ? 0.5f * (__cosf(PI_F * d / 20.f) + 1.f) : 0.f;
    csr_env[p] = ev;
    float base = PI_F * d / 20.f;
    #pragma unroll
    for (int k = 0; k < NRBF; ++k)
        csr_rbfe[(long)p * NRBF + k] = ev * __sinf((float)(k + 1) * base) * inv;
}

// ---------------------------------------------------------------------------
// Edge aggregation (R0-proven structure: 1 block/node, 128 thr, simple loop)
// ONLY change vs R0: inner loop hand-unrolled by 2 with all 12 gathers of
// the edge pair issued before any arithmetic -> doubles loads in flight.
// Accumulation order preserved exactly (edge A fully, then edge B), so
// results are bitwise identical to R0.
// ---------------------------------------------------------------------------
__global__ __launch_bounds__(128) void edge_aggr_kernel(
    const int* __restrict__ off, const int* __restrict__ csr_j,
    const float* __restrict__ csr_env, const float* __restrict__ csr_unit,
    const float* __restrict__ csr_rbfe,
    const ushort_t* __restrict__ phib, const float* __restrict__ vold,
    const float* __restrict__ distW, const float* __restrict__ distb,
    float* __restrict__ s, float* __restrict__ vnew,
    ushort_t* __restrict__ vnh, ushort_t* __restrict__ vnl, int N, int SP)
{
    const int f = threadIdx.x;
    float w0c[NRBF], w1c[NRBF], w2c[NRBF];
    const float b0 = distb[f];
    const float b1 = distb[128 + f];
    const float b2 = distb[256 + f];
    #pragma unroll
    for (int k = 0; k < NRBF; ++k) {
        w0c[k] = distW[(long)f * NRBF + k];
        w1c[k] = distW[(long)(128 + f) * NRBF + k];
        w2c[k] = distW[(long)(256 + f) * NRBF + k];
    }

    for (int node = blockIdx.x; node < N; node += gridDim.x) {
        const int p0 = off[node], p1 = off[node + 1];
        float ssum = 0.f, v0 = 0.f, v1 = 0.f, v2 = 0.f;

        int p = p0;
        for (; p + 1 < p1; p += 2) {
            // --- issue the edge pair's 12 gathers up front ---
            int jA = csr_j[p];
            int jB = csr_j[p + 1];
            long jbA = (long)jA * 384, jbB = (long)jB * 384;
            long jvA = (long)jA * FEAT + f, jvB = (long)jB * FEAT + f;
            float pA0 = b2f(phib[jbA + f]);
            float pA1 = b2f(phib[jbA + 128 + f]);
            float pA2 = b2f(phib[jbA + 256 + f]);
            float pB0 = b2f(phib[jbB + f]);
            float pB1 = b2f(phib[jbB + 128 + f]);
            float pB2 = b2f(phib[jbB + 256 + f]);
            float vA0 = vold[jvA];
            float vA1 = vold[SP + jvA];
            float vA2 = vold[2 * SP + jvA];
            float vB0 = vold[jvB];
            float vB1 = vold[SP + jvB];
            float vB2 = vold[2 * SP + jvB];

            // --- edge A (identical arithmetic/order to R0) ---
            {
                float ev = csr_env[p];
                float ux = csr_unit[3 * p + 0];
                float uy = csr_unit[3 * p + 1];
                float uz = csr_unit[3 * p + 2];
                const float* rb = csr_rbfe + (long)p * NRBF;
                float w0 = ev * b0, w1 = ev * b1, w2 = ev * b2;
                #pragma unroll
                for (int k = 0; k < NRBF; ++k) {
                    float r = rb[k];
                    w0 += r * w0c[k];
                    w1 += r * w1c[k];
                    w2 += r * w2c[k];
                }
                float i0 = pA0 * w0;
                float i1 = pA1 * w1;
                float i2 = pA2 * w2;
                ssum += i1;
                v0 += i2 * ux + i0 * vA0;
                v1 += i2 * uy + i0 * vA1;
                v2 += i2 * uz + i0 * vA2;
            }
            // --- edge B ---
            {
                int q = p + 1;
                float ev = csr_env[q];
                float ux = csr_unit[3 * q + 0];
                float uy = csr_unit[3 * q + 1];
                float uz = csr_unit[3 * q + 2];
                const float* rb = csr_rbfe + (long)q * NRBF;
                float w0 = ev * b0, w1 = ev * b1, w2 = ev * b2;
                #pragma unroll
                for (int k = 0; k < NRBF; ++k) {
                    float r = rb[k];
                    w0 += r * w0c[k];
                    w1 += r * w1c[k];
                    w2 += r * w2c[k];
                }
                float i0 = pB0 * w0;
                float i1 = pB1 * w1;
                float i2 = pB2 * w2;
                ssum += i1;
                v0 += i2 * ux + i0 * vB0;
                v1 += i2 * uy + i0 * vB1;
                v2 += i2 * uz + i0 * vB2;
            }
        }
        // --- tail single edge ---
        if (p < p1) {
            int j = csr_j[p];
            float ev = csr_env[p];
            float ux = csr_unit[3 * p + 0];
            float uy = csr_unit[3 * p + 1];
            float uz = csr_unit[3 * p + 2];
            const float* rb = csr_rbfe + (long)p * NRBF;
            float w0 = ev * b0, w1 = ev * b1, w2 = ev * b2;
            #pragma unroll
            for (int k = 0; k < NRBF; ++k) {
                float r = rb[k];
                w0 += r * w0c[k];
                w1 += r * w1c[k];
                w2 += r * w2c[k];
            }
            long jb = (long)j * 384;
            float i0 = b2f(phib[jb + f])       * w0;
            float i1 = b2f(phib[jb + 128 + f]) * w1;
            float i2 = b2f(phib[jb + 256 + f]) * w2;
            long jv = (long)j * FEAT + f;
            ssum += i1;
            v0 += i2 * ux + i0 * vold[jv];
            v1 += i2 * uy + i0 * vold[SP + jv];
            v2 += i2 * uz + i0 * vold[2 * SP + jv];
        }

        long iv = (long)node * FEAT + f;
        s[iv] += ssum;
        float n0 = vold[iv]          + v0;
        float n1 = vold[SP + iv]     + v1;
        float n2 = vold[2 * SP + iv] + v2;
        vnew[iv]          = n0;
        vnew[SP + iv]     = n1;
        vnew[2 * SP + iv] = n2;
        unsigned short h0 = f2b(n0), h1 = f2b(n1), h2 = f2b(n2);
        vnh[iv]          = h0;  vnl[iv]          = f2b(n0 - b2f(h0));
        vnh[SP + iv]     = h1;  vnl[SP + iv]     = f2b(n1 - b2f(h1));
        vnh[2 * SP + iv] = h2;  vnl[2 * SP + iv] = f2b(n2 - b2f(h2));
    }
}

// ---------------------------------------------------------------------------
// Elementwise kernels
// ---------------------------------------------------------------------------
__global__ __launch_bounds__(256) void init_s_kernel(
    const float* __restrict__ cg_s, float* __restrict__ s,
    float* __restrict__ vA, int nS, int nV)
{
    int idx = blockIdx.x * blockDim.x + threadIdx.x;
    if (idx < nS) s[idx] = cg_s[idx];
    if (idx < nV) vA[idx] = 0.f;
}

// final: if outv != null, v result goes interleaved to outv (and v not written)
__global__ __launch_bounds__(256) void update_sv_kernel(
    float* __restrict__ s, float* __restrict__ v,
    const float* __restrict__ uv, const float* __restrict__ vv,
    const float* __restrict__ a, float* __restrict__ outv, int SP)
{
    int idx = blockIdx.x * blockDim.x + threadIdx.x;
    if (idx >= SP) return;
    int n = idx >> 7, g = idx & 127;
    float u0 = uv[idx], u1 = uv[SP + idx], u2 = uv[2 * SP + idx];
    float w0 = vv[idx], w1 = vv[SP + idx], w2 = vv[2 * SP + idx];
    long ab = (long)n * 384;
    float dot = u0 * w0 + u1 * w1 + u2 * w2;
    s[idx] += dot * a[ab + 128 + g] + a[ab + 256 + g];
    float g0 = a[ab + g];
    float x0 = v[idx] + u0 * g0;
    float x1 = v[SP + idx] + u1 * g0;
    float x2 = v[2 * SP + idx] + u2 * g0;
    if (outv) {
        outv[(long)idx * 3 + 0] = x0;
        outv[(long)idx * 3 + 1] = x1;
        outv[(long)idx * 3 + 2] = x2;
    } else {
        v[idx]          = x0;
        v[SP + idx]     = x1;
        v[2 * SP + idx] = x2;
    }
}

// ---------------------------------------------------------------------------
extern "C" void kernel_launch(void* const* d_in, const int* in_sizes, int n_in,
                              void* d_out, int out_size, void* d_ws, size_t ws_size,
                              hipStream_t stream)
{
    const float* xyz     = (const float*)d_in[0];
    const int*   nbr     = (const int*)  d_in[1];
    const float* cg_s    = (const float*)d_in[2];
    const float* msg_W1  = (const float*)d_in[3];
    const float* msg_b1  = (const float*)d_in[4];
    const float* msg_W2  = (const float*)d_in[5];
    const float* msg_b2  = (const float*)d_in[6];
    const float* dist_W  = (const float*)d_in[7];
    const float* dist_b  = (const float*)d_in[8];
    const float* upd_U   = (const float*)d_in[9];
    const float* upd_V   = (const float*)d_in[10];
    const float* upd_sW1 = (const float*)d_in[11];
    const float* upd_sb1 = (const float*)d_in[12];
    const float* upd_sW2 = (const float*)d_in[13];
    const float* upd_sb2 = (const float*)d_in[14];

    const int E  = in_sizes[1] / 2;
    const int Ed = 2 * E;
    const int N  = in_sizes[2] / FEAT;
    const int SP = N * FEAT;

    float* s    = (float*)d_out;
    float* outv = (float*)d_out + (long)SP;

    // workspace carve-up
    float* w = (float*)d_ws;
    size_t off_ = 0;
    auto alloc = [&](size_t nelem) {
        float* p = w + off_;
        off_ += (nelem + 255) & ~(size_t)255;
        return p;
    };
    auto allocb = [&](size_t nelem) {
        return (ushort_t*)alloc((nelem + 1) / 2);
    };
    int*   deg      = (int*)alloc((size_t)N);
    int*   off      = (int*)alloc((size_t)N + 1);
    int*   cursor   = (int*)alloc((size_t)N);
    int*   csr_j    = (int*)alloc((size_t)Ed);
    float* csr_env  = alloc((size_t)Ed);
    float* csr_unit = alloc((size_t)Ed * 3);
    float* csr_rbfe = alloc((size_t)Ed * NRBF);
    float* a_buf    = alloc((size_t)N * 384);
    float* u_v      = alloc((size_t)3 * SP);
    float* v_v      = alloc((size_t)3 * SP);
    float* vA       = alloc((size_t)3 * SP);
    float* vB       = alloc((size_t)3 * SP);
    ushort_t* phi_b = allocb((size_t)N * 384);
    ushort_t* vnh   = allocb((size_t)3 * SP);
    ushort_t* vnl   = allocb((size_t)3 * SP);
    const int n1 = NCONV * FEAT * FEAT;
    const int n2 = NCONV * 3 * FEAT * FEAT;
    const int n3 = NCONV * FEAT * 2 * FEAT;
    ushort_t* w1h  = allocb((size_t)n1);
    ushort_t* w1l  = allocb((size_t)n1);
    ushort_t* w2h  = allocb((size_t)n2);
    ushort_t* w2l  = allocb((size_t)n2);
    ushort_t* uh   = allocb((size_t)n1);
    ushort_t* ul   = allocb((size_t)n1);
    ushort_t* vh   = allocb((size_t)n1);
    ushort_t* vl   = allocb((size_t)n1);
    ushort_t* sw1h = allocb((size_t)n3);
    ushort_t* sw1l = allocb((size_t)n3);
    ushort_t* sw2h = allocb((size_t)n2);
    ushort_t* sw2l = allocb((size_t)n2);
    (void)ws_size; (void)n_in; (void)out_size;

    // weight split (once per launch)
    split_kernel<<<(n1 + 255) / 256, 256, 0, stream>>>(msg_W1, w1h, w1l, n1);
    split_kernel<<<(n2 + 255) / 256, 256, 0, stream>>>(msg_W2, w2h, w2l, n2);
    split_kernel<<<(n1 + 255) / 256, 256, 0, stream>>>(upd_U, uh, ul, n1);
    split_kernel<<<(n1 + 255) / 256, 256, 0, stream>>>(upd_V, vh, vl, n1);
    split_kernel<<<(n3 + 255) / 256, 256, 0, stream>>>(upd_sW1, sw1h, sw1l, n3);
    split_kernel<<<(n2 + 255) / 256, 256, 0, stream>>>(upd_sW2, sw2h, sw2l, n2);

    // init s <- cg_s, vA <- 0
    {
        int n = 3 * SP;
        init_s_kernel<<<(n + 255) / 256, 256, 0, stream>>>(cg_s, s, vA, SP, n);
    }

    // CSR build (once per launch)
    hipMemsetAsync(deg, 0, (size_t)N * sizeof(int), stream);
    hist_kernel<<<(Ed + 255) / 256, 256, 0, stream>>>(nbr, deg, Ed);
    scan_kernel<<<1, 1024, 0, stream>>>(deg, off, cursor, N);
    scatter_geom_kernel<<<(Ed + 255) / 256, 256, 0, stream>>>(
        nbr, xyz, cursor, csr_j, csr_env, csr_unit, csr_rbfe, Ed);

    float* vold = vA;
    float* vnew = vB;
    dim3 gM((N + 127) / 128, 1);
    dim3 gUV((3 * N + 127) / 128, 2);

    for (int l = 0; l < NCONV; ++l) {
        const float* b1  = msg_b1  + (long)l * FEAT;
        const float* b2  = msg_b2  + (long)l * 3 * FEAT;
        const float* dW  = dist_W  + (long)l * 3 * FEAT * NRBF;
        const float* db  = dist_b  + (long)l * 3 * FEAT;
        const float* sb1 = upd_sb1 + (long)l * FEAT;
        const float* sb2 = upd_sb2 + (long)l * 3 * FEAT;
        const long o1 = (long)l * FEAT * FEAT;
        const long o2 = (long)l * 3 * FEAT * FEAT;
        const long o3 = (long)l * FEAT * 2 * FEAT;

        // fused phi-MLP: s -> (h in LDS) -> phi_b (bf16 hi)
        mlp_fused_kernel<<<gM, 256, 0, stream>>>(
            s, nullptr, w1h + o1, w1l + o1, b1, w2h + o2, w2l + o2, b2,
            phi_b, nullptr, N, FEAT, SP);

        // atomic-free message aggregation (R0 structure + pair-unroll)
        edge_aggr_kernel<<<N, 128, 0, stream>>>(
            off, csr_j, csr_env, csr_unit, csr_rbfe, phi_b, vold,
            dW, db, s, vnew, vnh, vnl, N, SP);

        // u_v / v_v in one dispatch (y=0 -> U, y=1 -> V)
        gemm_ps_kernel<<<gUV, 256, 0, stream>>>(
            vnh, vnl, uh + o1, ul + o1, vh + o1, vl + o1,
            u_v, v_v, 3 * N, FEAT);

        // fused gate-MLP: [s | norm(v_v)] -> (h in LDS) -> a_buf (fp32)
        mlp_fused_kernel<<<gM, 256, 0, stream>>>(
            s, v_v, sw1h + o3, sw1l + o3, sb1, sw2h + o2, sw2l + o2, sb2,
            nullptr, a_buf, N, 2 * FEAT, SP);

        // final update; last layer writes v interleaved straight to output
        float* ov = (l == NCONV - 1) ? outv : nullptr;
        update_sv_kernel<<<(SP + 255) / 256, 256, 0, stream>>>(
            s, vnew, u_v, v_v, a_buf, ov, SP);

        float* tmp = vold; vold = vnew; vnew = tmp;
    }
}

// Round 6
// 856.509 us; speedup vs baseline: 1.3261x; 1.2042x over previous
//
#include <hip/hip_runtime.h>
#include <math.h>

#define FEAT 128
#define NRBF 20
#define NCONV 3
#define PI_F 3.14159265358979323846f

typedef __attribute__((ext_vector_type(8))) short short8;
typedef __attribute__((ext_vector_type(4))) float floatx4;
typedef unsigned short ushort_t;

__device__ inline float b2f(unsigned short u) {
    union { unsigned int i; float f; } c; c.i = ((unsigned int)u) << 16; return c.f;
}
__device__ inline unsigned short f2b(float x) {
    union { float f; unsigned int i; } c; c.f = x;
    unsigned int u = c.i;
    return (unsigned short)((u + 0x7fffu + ((u >> 16) & 1u)) >> 16);
}

// ---------------------------------------------------------------------------
// Fused 2-layer MLP: out[M,384] = silu(A1 @ W1^T + b1) @ W2^T + b2
// A1 = s[M,128] (phi mode) or [s | norm(vv)] [M,256] (gate mode, vv != null).
// Hidden h lives in LDS hi/lo; never touches HBM.
// Split-precision: acc += Ah*Wh + Ah*Wl + Al*Wh throughout.
//
// R6: BM=64 (was 128). 256 thr = 4 waves; each wave computes 64 rows x a
// 32-col slice (acc[4][2]). grid = ceil(M/64) = 313 blocks -> all 256 CUs
// covered (was 157 blocks / ~100 idle CUs), LDS = 64 KB exactly -> 2
// blocks/CU (was 110 KB -> 1). Same arithmetic per element.
// ---------------------------------------------------------------------------
__global__ __launch_bounds__(256) void mlp_fused_kernel(
    const float* __restrict__ s, const float* __restrict__ vv,
    const ushort_t* __restrict__ W1h, const ushort_t* __restrict__ W1l,
    const float* __restrict__ b1,
    const ushort_t* __restrict__ W2h, const ushort_t* __restrict__ W2l,
    const float* __restrict__ b2,
    ushort_t* __restrict__ out_b, float* __restrict__ out_f,
    int M, int K1, int SP)
{
    __shared__ __align__(16) ushort_t Ah[64 * 40];
    __shared__ __align__(16) ushort_t Al[64 * 40];
    __shared__ __align__(16) ushort_t Wh[128 * 40];
    __shared__ __align__(16) ushort_t Wl[128 * 40];
    __shared__ __align__(16) ushort_t Hh[64 * 136];
    __shared__ __align__(16) ushort_t Hl[64 * 136];

    const int t    = threadIdx.x;
    const int m0   = blockIdx.x * 64;
    const int wv   = t >> 6;
    const int lane = t & 63;
    const int wn   = wv * 32;         // wave's 32-col slice
    const int lr   = lane & 15;
    const int lk   = (lane >> 4) * 8;
    const int quad = lane >> 4;
    const int arow = t >> 3;          // 0..31, 2 passes of 32 rows
    const int acol = (t & 7) * 4;     // fp32 x4
    const int wrow = t >> 2;          // 0..63, 2 passes of 64 rows
    const int wcol = (t & 3) * 8;     // ushort x8

    floatx4 acc[4][2] = {};

    // ---- stage 1: h = silu(A1 @ W1^T + b1) ----
    for (int k0 = 0; k0 < K1; k0 += 32) {
        #pragma unroll
        for (int h = 0; h < 2; ++h) {
            int r = arow + h * 32;
            int m = m0 + r; if (m >= M) m = M - 1;   // clamp tail
            float xs[4];
            if (k0 < 128) {
                float4 av = *(const float4*)(s + (long)m * 128 + k0 + acol);
                xs[0] = av.x; xs[1] = av.y; xs[2] = av.z; xs[3] = av.w;
            } else {
                long base = (long)m * 128 + (k0 - 128 + acol);
                float4 a0 = *(const float4*)(vv + base);
                float4 a1 = *(const float4*)(vv + (long)SP + base);
                float4 a2 = *(const float4*)(vv + 2 * (long)SP + base);
                xs[0] = sqrtf(a0.x * a0.x + a1.x * a1.x + a2.x * a2.x);
                xs[1] = sqrtf(a0.y * a0.y + a1.y * a1.y + a2.y * a2.y);
                xs[2] = sqrtf(a0.z * a0.z + a1.z * a1.z + a2.z * a2.z);
                xs[3] = sqrtf(a0.w * a0.w + a1.w * a1.w + a2.w * a2.w);
            }
            unsigned short hh[4], ll[4];
            #pragma unroll
            for (int q = 0; q < 4; ++q) {
                hh[q] = f2b(xs[q]);
                ll[q] = f2b(xs[q] - b2f(hh[q]));
            }
            *(ushort4*)(&Ah[r * 40 + acol]) = make_ushort4(hh[0], hh[1], hh[2], hh[3]);
            *(ushort4*)(&Al[r * 40 + acol]) = make_ushort4(ll[0], ll[1], ll[2], ll[3]);
        }
        #pragma unroll
        for (int h = 0; h < 2; ++h) {
            int r = wrow + h * 64;
            *(uint4*)(&Wh[r * 40 + wcol]) =
                *(const uint4*)(W1h + (long)r * K1 + k0 + wcol);
            *(uint4*)(&Wl[r * 40 + wcol]) =
                *(const uint4*)(W1l + (long)r * K1 + k0 + wcol);
        }
        __syncthreads();
        short8 af[4], alf[4], wf[2], wlf[2];
        #pragma unroll
        for (int i = 0; i < 4; ++i) {
            af[i]  = *(const short8*)(&Ah[(i * 16 + lr) * 40 + lk]);
            alf[i] = *(const short8*)(&Al[(i * 16 + lr) * 40 + lk]);
        }
        #pragma unroll
        for (int j = 0; j < 2; ++j) {
            wf[j]  = *(const short8*)(&Wh[(wn + j * 16 + lr) * 40 + lk]);
            wlf[j] = *(const short8*)(&Wl[(wn + j * 16 + lr) * 40 + lk]);
        }
        #pragma unroll
        for (int i = 0; i < 4; ++i)
            #pragma unroll
            for (int j = 0; j < 2; ++j) {
                acc[i][j] = __builtin_amdgcn_mfma_f32_16x16x32_bf16(
                    af[i], wf[j], acc[i][j], 0, 0, 0);
                acc[i][j] = __builtin_amdgcn_mfma_f32_16x16x32_bf16(
                    af[i], wlf[j], acc[i][j], 0, 0, 0);
                acc[i][j] = __builtin_amdgcn_mfma_f32_16x16x32_bf16(
                    alf[i], wf[j], acc[i][j], 0, 0, 0);
            }
        __syncthreads();
    }

    // stage-1 epilogue -> h in LDS (hi/lo), C/D layout col=lane&15, row=quad*4+r
    #pragma unroll
    for (int i = 0; i < 4; ++i)
        #pragma unroll
        for (int r = 0; r < 4; ++r) {
            int mrow = i * 16 + quad * 4 + r;
            #pragma unroll
            for (int j = 0; j < 2; ++j) {
                int kcol = wn + j * 16 + lr;
                float x = acc[i][j][r] + b1[kcol];
                x *= 1.f / (1.f + __expf(-x));
                unsigned short hh = f2b(x);
                Hh[mrow * 136 + kcol] = hh;
                Hl[mrow * 136 + kcol] = f2b(x - b2f(hh));
            }
        }

    // ---- stage 2: out = h @ W2^T + b2, 3 n-tiles of 128 ----
    for (int nt = 0; nt < 3; ++nt) {
        #pragma unroll
        for (int i = 0; i < 4; ++i)
            #pragma unroll
            for (int j = 0; j < 2; ++j)
                #pragma unroll
                for (int q = 0; q < 4; ++q) acc[i][j][q] = 0.f;
        for (int k0 = 0; k0 < 128; k0 += 32) {
            __syncthreads();   // guard Wh/Wl overwrite (and H writes on 1st pass)
            #pragma unroll
            for (int h = 0; h < 2; ++h) {
                int r = wrow + h * 64;
                long wo = (long)(nt * 128 + r) * 128;
                *(uint4*)(&Wh[r * 40 + wcol]) = *(const uint4*)(W2h + wo + k0 + wcol);
                *(uint4*)(&Wl[r * 40 + wcol]) = *(const uint4*)(W2l + wo + k0 + wcol);
            }
            __syncthreads();
            short8 af[4], alf[4], wf[2], wlf[2];
            #pragma unroll
            for (int i = 0; i < 4; ++i) {
                af[i]  = *(const short8*)(&Hh[(i * 16 + lr) * 136 + k0 + lk]);
                alf[i] = *(const short8*)(&Hl[(i * 16 + lr) * 136 + k0 + lk]);
            }
            #pragma unroll
            for (int j = 0; j < 2; ++j) {
                wf[j]  = *(const short8*)(&Wh[(wn + j * 16 + lr) * 40 + lk]);
                wlf[j] = *(const short8*)(&Wl[(wn + j * 16 + lr) * 40 + lk]);
            }
            #pragma unroll
            for (int i = 0; i < 4; ++i)
                #pragma unroll
                for (int j = 0; j < 2; ++j) {
                    acc[i][j] = __builtin_amdgcn_mfma_f32_16x16x32_bf16(
                        af[i], wf[j], acc[i][j], 0, 0, 0);
                    acc[i][j] = __builtin_amdgcn_mfma_f32_16x16x32_bf16(
                        af[i], wlf[j], acc[i][j], 0, 0, 0);
                    acc[i][j] = __builtin_amdgcn_mfma_f32_16x16x32_bf16(
                        alf[i], wf[j], acc[i][j], 0, 0, 0);
                }
        }
        #pragma unroll
        for (int i = 0; i < 4; ++i)
            #pragma unroll
            for (int r = 0; r < 4; ++r) {
                int m = m0 + i * 16 + quad * 4 + r;
                if (m >= M) continue;
                #pragma unroll
                for (int j = 0; j < 2; ++j) {
                    int n = nt * 128 + wn + j * 16 + lr;
                    float x = acc[i][j][r] + b2[n];
                    if (out_b) out_b[(long)m * 384 + n] = f2b(x);
                    else       out_f[(long)m * 384 + n] = x;
                }
            }
    }
}

// ---------------------------------------------------------------------------
// Pre-split MFMA GEMM (UV only): dual weights, fp32 C0/C1 routing by n-tile.
// ---------------------------------------------------------------------------
__global__ __launch_bounds__(256) void gemm_ps_kernel(
    const ushort_t* __restrict__ Ahg, const ushort_t* __restrict__ Alg,
    const ushort_t* __restrict__ Whi, const ushort_t* __restrict__ Wlo,
    const ushort_t* __restrict__ W2h, const ushort_t* __restrict__ W2l,
    float* __restrict__ C0, float* __restrict__ C1,
    int M, int K)
{
    __shared__ __align__(16) ushort_t Ah[128 * 40];
    __shared__ __align__(16) ushort_t Al[128 * 40];
    __shared__ __align__(16) ushort_t Wh[128 * 40];
    __shared__ __align__(16) ushort_t Wl[128 * 40];
    const int t    = threadIdx.x;
    const int m0   = blockIdx.x * 128;
    const int nt   = blockIdx.y;          // 0 -> U/C0, 1 -> V/C1
    const int wv   = t >> 6;
    const int lane = t & 63;
    const int wm   = (wv >> 1) * 64;
    const int wn   = (wv & 1) * 64;
    const int lr   = lane & 15;
    const int lk   = (lane >> 4) * 8;
    const int srow = t >> 2;
    const int scol = (t & 3) * 8;
    const ushort_t* Wsh = nt ? W2h : Whi;
    const ushort_t* Wsl = nt ? W2l : Wlo;

    floatx4 acc[4][4] = {};

    for (int k0 = 0; k0 < K; k0 += 32) {
        #pragma unroll
        for (int h = 0; h < 2; ++h) {
            int r = srow + h * 64;
            int m = m0 + r; if (m >= M) m = M - 1;
            *(uint4*)(&Ah[r * 40 + scol]) =
                *(const uint4*)(Ahg + (long)m * K + k0 + scol);
            *(uint4*)(&Al[r * 40 + scol]) =
                *(const uint4*)(Alg + (long)m * K + k0 + scol);
            *(uint4*)(&Wh[r * 40 + scol]) =
                *(const uint4*)(Wsh + (long)r * K + k0 + scol);
            *(uint4*)(&Wl[r * 40 + scol]) =
                *(const uint4*)(Wsl + (long)r * K + k0 + scol);
        }
        __syncthreads();
        short8 ah[4], al[4], wh[4], wl[4];
        #pragma unroll
        for (int i = 0; i < 4; ++i) {
            ah[i] = *(const short8*)(&Ah[(wm + i * 16 + lr) * 40 + lk]);
            al[i] = *(const short8*)(&Al[(wm + i * 16 + lr) * 40 + lk]);
            wh[i] = *(const short8*)(&Wh[(wn + i * 16 + lr) * 40 + lk]);
            wl[i] = *(const short8*)(&Wl[(wn + i * 16 + lr) * 40 + lk]);
        }
        #pragma unroll
        for (int i = 0; i < 4; ++i)
            #pragma unroll
            for (int j = 0; j < 4; ++j) {
                acc[i][j] = __builtin_amdgcn_mfma_f32_16x16x32_bf16(
                    ah[i], wh[j], acc[i][j], 0, 0, 0);
                acc[i][j] = __builtin_amdgcn_mfma_f32_16x16x32_bf16(
                    ah[i], wl[j], acc[i][j], 0, 0, 0);
                acc[i][j] = __builtin_amdgcn_mfma_f32_16x16x32_bf16(
                    al[i], wh[j], acc[i][j], 0, 0, 0);
            }
        __syncthreads();
    }

    float* C = nt ? C1 : C0;
    #pragma unroll
    for (int i = 0; i < 4; ++i)
        #pragma unroll
        for (int r = 0; r < 4; ++r) {
            int m = m0 + wm + i * 16 + (lane >> 4) * 4 + r;
            if (m >= M) continue;
            #pragma unroll
            for (int j = 0; j < 4; ++j) {
                int n = wn + j * 16 + lr;
                C[(long)m * 128 + n] = acc[i][j][r];
            }
        }
}

// ---------------------------------------------------------------------------
__global__ __launch_bounds__(256) void split_kernel(
    const float* __restrict__ src, ushort_t* __restrict__ hi,
    ushort_t* __restrict__ lo, int n)
{
    int i = blockIdx.x * blockDim.x + threadIdx.x;
    if (i >= n) return;
    float x = src[i];
    unsigned short h = f2b(x);
    hi[i] = h;
    lo[i] = f2b(x - b2f(h));
}

// ---------------------------------------------------------------------------
// CSR build
// ---------------------------------------------------------------------------
__global__ __launch_bounds__(256) void hist_kernel(
    const int* __restrict__ nbr, int* __restrict__ deg, int Ed)
{
    int e = blockIdx.x * blockDim.x + threadIdx.x;
    if (e >= Ed) return;
    int E = Ed >> 1;
    int i = (e < E) ? nbr[2 * e] : nbr[2 * (e - E) + 1];
    atomicAdd(&deg[i], 1);
}

__device__ inline int wave_incl_scan(int x, int lane)
{
    #pragma unroll
    for (int s = 1; s < 64; s <<= 1) {
        int y = __shfl_up(x, s, 64);
        if (lane >= s) x += y;
    }
    return x;
}

__global__ __launch_bounds__(1024) void scan_kernel(
    const int* __restrict__ deg, int* __restrict__ off,
    int* __restrict__ cursor, int N)
{
    __shared__ int wsum[16];
    __shared__ int carry_s;
    const int t = threadIdx.x;
    const int lane = t & 63;
    const int w = t >> 6;
    if (t == 0) { carry_s = 0; off[0] = 0; }
    __syncthreads();
    for (int base = 0; base < N; base += 1024) {
        int i = base + t;
        int x = (i < N) ? deg[i] : 0;
        int sc = wave_incl_scan(x, lane);
        if (lane == 63) wsum[w] = sc;
        __syncthreads();
        if (w == 0) {
            int v = (lane < 16) ? wsum[lane] : 0;
            int vs = wave_incl_scan(v, lane);
            if (lane < 16) wsum[lane] = vs;
        }
        __syncthreads();
        int waveoff = (w > 0) ? wsum[w - 1] : 0;
        int inc = sc + waveoff + carry_s;
        if (i < N) { off[i + 1] = inc; cursor[i] = inc - x; }
        __syncthreads();
        if (t == 1023) carry_s = inc;
        __syncthreads();
    }
}

__global__ __launch_bounds__(256) void scatter_geom_kernel(
    const int* __restrict__ nbr, const float* __restrict__ xyz,
    int* __restrict__ cursor, int* __restrict__ csr_j,
    float* __restrict__ csr_env, float* __restrict__ csr_unit,
    float* __restrict__ csr_rbfe, int Ed)
{
    int e = blockIdx.x * blockDim.x + threadIdx.x;
    if (e >= Ed) return;
    int E = Ed >> 1;
    int i, j;
    if (e < E) { i = nbr[2 * e];         j = nbr[2 * e + 1]; }
    else       { int u = e - E; i = nbr[2 * u + 1]; j = nbr[2 * u]; }

    int p = atomicAdd(&cursor[i], 1);
    csr_j[p] = j;

    float rx = xyz[3 * j + 0] - xyz[3 * i + 0];
    float ry = xyz[3 * j + 1] - xyz[3 * i + 1];
    float rz = xyz[3 * j + 2] - xyz[3 * i + 2];
    float d   = sqrtf(rx * rx + ry * ry + rz * rz);
    float inv = 1.f / d;
    csr_unit[3 * p + 0] = rx * inv;
    csr_unit[3 * p + 1] = ry * inv;
    csr_unit[3 * p + 2] = rz * inv;
    float ev = (d < 20.f) ? 0.5f * (__cosf(PI_F * d / 20.f) + 1.f) : 0.f;
    csr_env[p] = ev;
    float base = PI_F * d / 20.f;
    #pragma unroll
    for (int k = 0; k < NRBF; ++k)
        csr_rbfe[(long)p * NRBF + k] = ev * __sinf((float)(k + 1) * base) * inv;
}

// ---------------------------------------------------------------------------
// Edge aggregation — EXACT R0 structure (proven best: VGPR 52, occ 37%,
// ~108 us). Five variants (LDS coeffs, packed gathers, persistent blocks,
// pair-unroll) all regressed via lower occupancy; do not touch.
// ---------------------------------------------------------------------------
__global__ __launch_bounds__(128) void edge_aggr_kernel(
    const int* __restrict__ off, const int* __restrict__ csr_j,
    const float* __restrict__ csr_env, const float* __restrict__ csr_unit,
    const float* __restrict__ csr_rbfe,
    const ushort_t* __restrict__ phib, const float* __restrict__ vold,
    const float* __restrict__ distW, const float* __restrict__ distb,
    float* __restrict__ s, float* __restrict__ vnew,
    ushort_t* __restrict__ vnh, ushort_t* __restrict__ vnl, int N, int SP)
{
    const int f = threadIdx.x;
    float w0c[NRBF], w1c[NRBF], w2c[NRBF];
    const float b0 = distb[f];
    const float b1 = distb[128 + f];
    const float b2 = distb[256 + f];
    #pragma unroll
    for (int k = 0; k < NRBF; ++k) {
        w0c[k] = distW[(long)f * NRBF + k];
        w1c[k] = distW[(long)(128 + f) * NRBF + k];
        w2c[k] = distW[(long)(256 + f) * NRBF + k];
    }

    for (int node = blockIdx.x; node < N; node += gridDim.x) {
        const int p0 = off[node], p1 = off[node + 1];
        float ssum = 0.f, v0 = 0.f, v1 = 0.f, v2 = 0.f;
        for (int p = p0; p < p1; ++p) {
            int j = csr_j[p];
            float ev = csr_env[p];
            float ux = csr_unit[3 * p + 0];
            float uy = csr_unit[3 * p + 1];
            float uz = csr_unit[3 * p + 2];
            const float* rb = csr_rbfe + (long)p * NRBF;
            float w0 = ev * b0, w1 = ev * b1, w2 = ev * b2;
            #pragma unroll
            for (int k = 0; k < NRBF; ++k) {
                float r = rb[k];
                w0 += r * w0c[k];
                w1 += r * w1c[k];
                w2 += r * w2c[k];
            }
            long jb = (long)j * 384;
            float i0 = b2f(phib[jb + f])       * w0;
            float i1 = b2f(phib[jb + 128 + f]) * w1;
            float i2 = b2f(phib[jb + 256 + f]) * w2;
            long jv = (long)j * FEAT + f;
            ssum += i1;
            v0 += i2 * ux + i0 * vold[jv];
            v1 += i2 * uy + i0 * vold[SP + jv];
            v2 += i2 * uz + i0 * vold[2 * SP + jv];
        }
        long iv = (long)node * FEAT + f;
        s[iv] += ssum;
        float n0 = vold[iv]          + v0;
        float n1 = vold[SP + iv]     + v1;
        float n2 = vold[2 * SP + iv] + v2;
        vnew[iv]          = n0;
        vnew[SP + iv]     = n1;
        vnew[2 * SP + iv] = n2;
        unsigned short h0 = f2b(n0), h1 = f2b(n1), h2 = f2b(n2);
        vnh[iv]          = h0;  vnl[iv]          = f2b(n0 - b2f(h0));
        vnh[SP + iv]     = h1;  vnl[SP + iv]     = f2b(n1 - b2f(h1));
        vnh[2 * SP + iv] = h2;  vnl[2 * SP + iv] = f2b(n2 - b2f(h2));
    }
}

// ---------------------------------------------------------------------------
// Elementwise kernels
// ---------------------------------------------------------------------------
__global__ __launch_bounds__(256) void init_s_kernel(
    const float* __restrict__ cg_s, float* __restrict__ s,
    float* __restrict__ vA, int nS, int nV)
{
    int idx = blockIdx.x * blockDim.x + threadIdx.x;
    if (idx < nS) s[idx] = cg_s[idx];
    if (idx < nV) vA[idx] = 0.f;
}

// final: if outv != null, v result goes interleaved to outv (and v not written)
__global__ __launch_bounds__(256) void update_sv_kernel(
    float* __restrict__ s, float* __restrict__ v,
    const float* __restrict__ uv, const float* __restrict__ vv,
    const float* __restrict__ a, float* __restrict__ outv, int SP)
{
    int idx = blockIdx.x * blockDim.x + threadIdx.x;
    if (idx >= SP) return;
    int n = idx >> 7, g = idx & 127;
    float u0 = uv[idx], u1 = uv[SP + idx], u2 = uv[2 * SP + idx];
    float w0 = vv[idx], w1 = vv[SP + idx], w2 = vv[2 * SP + idx];
    long ab = (long)n * 384;
    float dot = u0 * w0 + u1 * w1 + u2 * w2;
    s[idx] += dot * a[ab + 128 + g] + a[ab + 256 + g];
    float g0 = a[ab + g];
    float x0 = v[idx] + u0 * g0;
    float x1 = v[SP + idx] + u1 * g0;
    float x2 = v[2 * SP + idx] + u2 * g0;
    if (outv) {
        outv[(long)idx * 3 + 0] = x0;
        outv[(long)idx * 3 + 1] = x1;
        outv[(long)idx * 3 + 2] = x2;
    } else {
        v[idx]          = x0;
        v[SP + idx]     = x1;
        v[2 * SP + idx] = x2;
    }
}

// ---------------------------------------------------------------------------
extern "C" void kernel_launch(void* const* d_in, const int* in_sizes, int n_in,
                              void* d_out, int out_size, void* d_ws, size_t ws_size,
                              hipStream_t stream)
{
    const float* xyz     = (const float*)d_in[0];
    const int*   nbr     = (const int*)  d_in[1];
    const float* cg_s    = (const float*)d_in[2];
    const float* msg_W1  = (const float*)d_in[3];
    const float* msg_b1  = (const float*)d_in[4];
    const float* msg_W2  = (const float*)d_in[5];
    const float* msg_b2  = (const float*)d_in[6];
    const float* dist_W  = (const float*)d_in[7];
    const float* dist_b  = (const float*)d_in[8];
    const float* upd_U   = (const float*)d_in[9];
    const float* upd_V   = (const float*)d_in[10];
    const float* upd_sW1 = (const float*)d_in[11];
    const float* upd_sb1 = (const float*)d_in[12];
    const float* upd_sW2 = (const float*)d_in[13];
    const float* upd_sb2 = (const float*)d_in[14];

    const int E  = in_sizes[1] / 2;
    const int Ed = 2 * E;
    const int N  = in_sizes[2] / FEAT;
    const int SP = N * FEAT;

    float* s    = (float*)d_out;
    float* outv = (float*)d_out + (long)SP;

    // workspace carve-up
    float* w = (float*)d_ws;
    size_t off_ = 0;
    auto alloc = [&](size_t nelem) {
        float* p = w + off_;
        off_ += (nelem + 255) & ~(size_t)255;
        return p;
    };
    auto allocb = [&](size_t nelem) {
        return (ushort_t*)alloc((nelem + 1) / 2);
    };
    int*   deg      = (int*)alloc((size_t)N);
    int*   off      = (int*)alloc((size_t)N + 1);
    int*   cursor   = (int*)alloc((size_t)N);
    int*   csr_j    = (int*)alloc((size_t)Ed);
    float* csr_env  = alloc((size_t)Ed);
    float* csr_unit = alloc((size_t)Ed * 3);
    float* csr_rbfe = alloc((size_t)Ed * NRBF);
    float* a_buf    = alloc((size_t)N * 384);
    float* u_v      = alloc((size_t)3 * SP);
    float* v_v      = alloc((size_t)3 * SP);
    float* vA       = alloc((size_t)3 * SP);
    float* vB       = alloc((size_t)3 * SP);
    ushort_t* phi_b = allocb((size_t)N * 384);
    ushort_t* vnh   = allocb((size_t)3 * SP);
    ushort_t* vnl   = allocb((size_t)3 * SP);
    const int n1 = NCONV * FEAT * FEAT;
    const int n2 = NCONV * 3 * FEAT * FEAT;
    const int n3 = NCONV * FEAT * 2 * FEAT;
    ushort_t* w1h  = allocb((size_t)n1);
    ushort_t* w1l  = allocb((size_t)n1);
    ushort_t* w2h  = allocb((size_t)n2);
    ushort_t* w2l  = allocb((size_t)n2);
    ushort_t* uh   = allocb((size_t)n1);
    ushort_t* ul   = allocb((size_t)n1);
    ushort_t* vh   = allocb((size_t)n1);
    ushort_t* vl   = allocb((size_t)n1);
    ushort_t* sw1h = allocb((size_t)n3);
    ushort_t* sw1l = allocb((size_t)n3);
    ushort_t* sw2h = allocb((size_t)n2);
    ushort_t* sw2l = allocb((size_t)n2);
    (void)ws_size; (void)n_in; (void)out_size;

    // weight split (once per launch)
    split_kernel<<<(n1 + 255) / 256, 256, 0, stream>>>(msg_W1, w1h, w1l, n1);
    split_kernel<<<(n2 + 255) / 256, 256, 0, stream>>>(msg_W2, w2h, w2l, n2);
    split_kernel<<<(n1 + 255) / 256, 256, 0, stream>>>(upd_U, uh, ul, n1);
    split_kernel<<<(n1 + 255) / 256, 256, 0, stream>>>(upd_V, vh, vl, n1);
    split_kernel<<<(n3 + 255) / 256, 256, 0, stream>>>(upd_sW1, sw1h, sw1l, n3);
    split_kernel<<<(n2 + 255) / 256, 256, 0, stream>>>(upd_sW2, sw2h, sw2l, n2);

    // init s <- cg_s, vA <- 0
    {
        int n = 3 * SP;
        init_s_kernel<<<(n + 255) / 256, 256, 0, stream>>>(cg_s, s, vA, SP, n);
    }

    // CSR build (once per launch)
    hipMemsetAsync(deg, 0, (size_t)N * sizeof(int), stream);
    hist_kernel<<<(Ed + 255) / 256, 256, 0, stream>>>(nbr, deg, Ed);
    scan_kernel<<<1, 1024, 0, stream>>>(deg, off, cursor, N);
    scatter_geom_kernel<<<(Ed + 255) / 256, 256, 0, stream>>>(
        nbr, xyz, cursor, csr_j, csr_env, csr_unit, csr_rbfe, Ed);

    float* vold = vA;
    float* vnew = vB;
    dim3 gM((N + 63) / 64, 1);
    dim3 gUV((3 * N + 127) / 128, 2);

    for (int l = 0; l < NCONV; ++l) {
        const float* b1  = msg_b1  + (long)l * FEAT;
        const float* b2  = msg_b2  + (long)l * 3 * FEAT;
        const float* dW  = dist_W  + (long)l * 3 * FEAT * NRBF;
        const float* db  = dist_b  + (long)l * 3 * FEAT;
        const float* sb1 = upd_sb1 + (long)l * FEAT;
        const float* sb2 = upd_sb2 + (long)l * 3 * FEAT;
        const long o1 = (long)l * FEAT * FEAT;
        const long o2 = (long)l * 3 * FEAT * FEAT;
        const long o3 = (long)l * FEAT * 2 * FEAT;

        // fused phi-MLP: s -> (h in LDS) -> phi_b (bf16 hi)
        mlp_fused_kernel<<<gM, 256, 0, stream>>>(
            s, nullptr, w1h + o1, w1l + o1, b1, w2h + o2, w2l + o2, b2,
            phi_b, nullptr, N, FEAT, SP);

        // atomic-free message aggregation (exact R0)
        edge_aggr_kernel<<<N, 128, 0, stream>>>(
            off, csr_j, csr_env, csr_unit, csr_rbfe, phi_b, vold,
            dW, db, s, vnew, vnh, vnl, N, SP);

        // u_v / v_v in one dispatch (y=0 -> U, y=1 -> V)
        gemm_ps_kernel<<<gUV, 256, 0, stream>>>(
            vnh, vnl, uh + o1, ul + o1, vh + o1, vl + o1,
            u_v, v_v, 3 * N, FEAT);

        // fused gate-MLP: [s | norm(v_v)] -> (h in LDS) -> a_buf (fp32)
        mlp_fused_kernel<<<gM, 256, 0, stream>>>(
            s, v_v, sw1h + o3, sw1l + o3, sb1, sw2h + o2, sw2l + o2, sb2,
            nullptr, a_buf, N, 2 * FEAT, SP);

        // final update; last layer writes v interleaved straight to output
        float* ov = (l == NCONV - 1) ? outv : nullptr;
        update_sv_kernel<<<(SP + 255) / 256, 256, 0, stream>>>(
            s, vnew, u_v, v_v, a_buf, ov, SP);

        float* tmp = vold; vold = vnew; vnew = tmp;
    }
}

// Round 7
// 793.144 us; speedup vs baseline: 1.4321x; 1.0799x over previous
//
#include <hip/hip_runtime.h>
#include <math.h>

#define FEAT 128
#define NRBF 20
#define NCONV 3
#define PI_F 3.14159265358979323846f

typedef __attribute__((ext_vector_type(8))) short short8;
typedef __attribute__((ext_vector_type(4))) float floatx4;
typedef unsigned short ushort_t;

__device__ inline float b2f(unsigned short u) {
    union { unsigned int i; float f; } c; c.i = ((unsigned int)u) << 16; return c.f;
}
__device__ inline unsigned short f2b(float x) {
    union { float f; unsigned int i; } c; c.f = x;
    unsigned int u = c.i;
    return (unsigned short)((u + 0x7fffu + ((u >> 16) & 1u)) >> 16);
}

// ---------------------------------------------------------------------------
// Fused 2-layer MLP: out[M,384] = silu(A1 @ W1^T + b1) @ W2^T + b2
// A1 = s[M,128] (phi mode) or [s | norm(vv)] [M,256] (gate mode).
// BM=64, 256 thr = 4 waves, per-wave 64x32 slice (acc[4][2]); LDS 64 KB ->
// 2 blocks/CU; grid ceil(M/64) covers all 256 CUs.  (R6 structure, proven.)
//
// R7: FUSED=1 (gate mode) keeps stage-2 accumulators across all 3 n-tiles
// (accS[3][4][2], statically indexed via unrolled nt) and applies the
// update_sv arithmetic in the epilogue:
//   a_c = acc_c + b2[c*128+g]  (identical values to the old a_buf)
//   s  += (u.w)*a1 + a2 ;  v += u*a0  (or interleaved outv on last layer)
// Eliminates a_buf entirely (30 MB write + 30 MB read per layer) and the
// 3 update_sv dispatches. Blocks touch only their own 64 rows -> race-free.
// ---------------------------------------------------------------------------
template<int FUSED>
__global__ __launch_bounds__(256, 2) void mlp_fused_kernel(
    const float* __restrict__ s, const float* __restrict__ vv,
    const ushort_t* __restrict__ W1h, const ushort_t* __restrict__ W1l,
    const float* __restrict__ b1,
    const ushort_t* __restrict__ W2h, const ushort_t* __restrict__ W2l,
    const float* __restrict__ b2,
    ushort_t* __restrict__ out_b,
    const float* __restrict__ uv,      // FUSED: u_v planar 3xSP
    float* s_out, float* vbuf,         // FUSED: s (rw), v (rw, planar 3xSP)
    float* outv,                       // FUSED last layer: interleaved out
    int M, int K1, int SP)
{
    __shared__ __align__(16) ushort_t Ah[64 * 40];
    __shared__ __align__(16) ushort_t Al[64 * 40];
    __shared__ __align__(16) ushort_t Wh[128 * 40];
    __shared__ __align__(16) ushort_t Wl[128 * 40];
    __shared__ __align__(16) ushort_t Hh[64 * 136];
    __shared__ __align__(16) ushort_t Hl[64 * 136];

    const int t    = threadIdx.x;
    const int m0   = blockIdx.x * 64;
    const int wv   = t >> 6;
    const int lane = t & 63;
    const int wn   = wv * 32;         // wave's 32-col slice
    const int lr   = lane & 15;
    const int lk   = (lane >> 4) * 8;
    const int quad = lane >> 4;
    const int arow = t >> 3;          // 0..31, 2 passes of 32 rows
    const int acol = (t & 7) * 4;     // fp32 x4
    const int wrow = t >> 2;          // 0..63, 2 passes of 64 rows
    const int wcol = (t & 3) * 8;     // ushort x8

    floatx4 acc[4][2] = {};

    // ---- stage 1: h = silu(A1 @ W1^T + b1) ----
    for (int k0 = 0; k0 < K1; k0 += 32) {
        #pragma unroll
        for (int h = 0; h < 2; ++h) {
            int r = arow + h * 32;
            int m = m0 + r; if (m >= M) m = M - 1;   // clamp tail (in-block)
            float xs[4];
            if (k0 < 128) {
                float4 av = *(const float4*)(s + (long)m * 128 + k0 + acol);
                xs[0] = av.x; xs[1] = av.y; xs[2] = av.z; xs[3] = av.w;
            } else {
                long base = (long)m * 128 + (k0 - 128 + acol);
                float4 a0 = *(const float4*)(vv + base);
                float4 a1 = *(const float4*)(vv + (long)SP + base);
                float4 a2 = *(const float4*)(vv + 2 * (long)SP + base);
                xs[0] = sqrtf(a0.x * a0.x + a1.x * a1.x + a2.x * a2.x);
                xs[1] = sqrtf(a0.y * a0.y + a1.y * a1.y + a2.y * a2.y);
                xs[2] = sqrtf(a0.z * a0.z + a1.z * a1.z + a2.z * a2.z);
                xs[3] = sqrtf(a0.w * a0.w + a1.w * a1.w + a2.w * a2.w);
            }
            unsigned short hh[4], ll[4];
            #pragma unroll
            for (int q = 0; q < 4; ++q) {
                hh[q] = f2b(xs[q]);
                ll[q] = f2b(xs[q] - b2f(hh[q]));
            }
            *(ushort4*)(&Ah[r * 40 + acol]) = make_ushort4(hh[0], hh[1], hh[2], hh[3]);
            *(ushort4*)(&Al[r * 40 + acol]) = make_ushort4(ll[0], ll[1], ll[2], ll[3]);
        }
        #pragma unroll
        for (int h = 0; h < 2; ++h) {
            int r = wrow + h * 64;
            *(uint4*)(&Wh[r * 40 + wcol]) =
                *(const uint4*)(W1h + (long)r * K1 + k0 + wcol);
            *(uint4*)(&Wl[r * 40 + wcol]) =
                *(const uint4*)(W1l + (long)r * K1 + k0 + wcol);
        }
        __syncthreads();
        short8 af[4], alf[4], wf[2], wlf[2];
        #pragma unroll
        for (int i = 0; i < 4; ++i) {
            af[i]  = *(const short8*)(&Ah[(i * 16 + lr) * 40 + lk]);
            alf[i] = *(const short8*)(&Al[(i * 16 + lr) * 40 + lk]);
        }
        #pragma unroll
        for (int j = 0; j < 2; ++j) {
            wf[j]  = *(const short8*)(&Wh[(wn + j * 16 + lr) * 40 + lk]);
            wlf[j] = *(const short8*)(&Wl[(wn + j * 16 + lr) * 40 + lk]);
        }
        #pragma unroll
        for (int i = 0; i < 4; ++i)
            #pragma unroll
            for (int j = 0; j < 2; ++j) {
                acc[i][j] = __builtin_amdgcn_mfma_f32_16x16x32_bf16(
                    af[i], wf[j], acc[i][j], 0, 0, 0);
                acc[i][j] = __builtin_amdgcn_mfma_f32_16x16x32_bf16(
                    af[i], wlf[j], acc[i][j], 0, 0, 0);
                acc[i][j] = __builtin_amdgcn_mfma_f32_16x16x32_bf16(
                    alf[i], wf[j], acc[i][j], 0, 0, 0);
            }
        __syncthreads();
    }

    // stage-1 epilogue -> h in LDS (hi/lo), C/D layout col=lane&15, row=quad*4+r
    #pragma unroll
    for (int i = 0; i < 4; ++i)
        #pragma unroll
        for (int r = 0; r < 4; ++r) {
            int mrow = i * 16 + quad * 4 + r;
            #pragma unroll
            for (int j = 0; j < 2; ++j) {
                int kcol = wn + j * 16 + lr;
                float x = acc[i][j][r] + b1[kcol];
                x *= 1.f / (1.f + __expf(-x));
                unsigned short hh = f2b(x);
                Hh[mrow * 136 + kcol] = hh;
                Hl[mrow * 136 + kcol] = f2b(x - b2f(hh));
            }
        }

    // ---- stage 2: 3 n-tiles of 128; FUSED keeps all accumulators ----
    floatx4 accS[3][4][2];
    #pragma unroll
    for (int nt = 0; nt < 3; ++nt) {
        floatx4 a2c[4][2] = {};
        for (int k0 = 0; k0 < 128; k0 += 32) {
            __syncthreads();   // guard Wh/Wl overwrite (and H writes on 1st pass)
            #pragma unroll
            for (int h = 0; h < 2; ++h) {
                int r = wrow + h * 64;
                long wo = (long)(nt * 128 + r) * 128;
                *(uint4*)(&Wh[r * 40 + wcol]) = *(const uint4*)(W2h + wo + k0 + wcol);
                *(uint4*)(&Wl[r * 40 + wcol]) = *(const uint4*)(W2l + wo + k0 + wcol);
            }
            __syncthreads();
            short8 af[4], alf[4], wf[2], wlf[2];
            #pragma unroll
            for (int i = 0; i < 4; ++i) {
                af[i]  = *(const short8*)(&Hh[(i * 16 + lr) * 136 + k0 + lk]);
                alf[i] = *(const short8*)(&Hl[(i * 16 + lr) * 136 + k0 + lk]);
            }
            #pragma unroll
            for (int j = 0; j < 2; ++j) {
                wf[j]  = *(const short8*)(&Wh[(wn + j * 16 + lr) * 40 + lk]);
                wlf[j] = *(const short8*)(&Wl[(wn + j * 16 + lr) * 40 + lk]);
            }
            #pragma unroll
            for (int i = 0; i < 4; ++i)
                #pragma unroll
                for (int j = 0; j < 2; ++j) {
                    a2c[i][j] = __builtin_amdgcn_mfma_f32_16x16x32_bf16(
                        af[i], wf[j], a2c[i][j], 0, 0, 0);
                    a2c[i][j] = __builtin_amdgcn_mfma_f32_16x16x32_bf16(
                        af[i], wlf[j], a2c[i][j], 0, 0, 0);
                    a2c[i][j] = __builtin_amdgcn_mfma_f32_16x16x32_bf16(
                        alf[i], wf[j], a2c[i][j], 0, 0, 0);
                }
        }
        if (FUSED) {
            #pragma unroll
            for (int i = 0; i < 4; ++i)
                #pragma unroll
                for (int j = 0; j < 2; ++j)
                    accS[nt][i][j] = a2c[i][j];
        } else {
            #pragma unroll
            for (int i = 0; i < 4; ++i)
                #pragma unroll
                for (int r = 0; r < 4; ++r) {
                    int m = m0 + i * 16 + quad * 4 + r;
                    if (m >= M) continue;
                    #pragma unroll
                    for (int j = 0; j < 2; ++j) {
                        int n = nt * 128 + wn + j * 16 + lr;
                        out_b[(long)m * 384 + n] = f2b(a2c[i][j][r] + b2[n]);
                    }
                }
        }
    }

    // ---- fused update epilogue (gate mode): update_sv arithmetic in-place ----
    if (FUSED) {
        #pragma unroll
        for (int i = 0; i < 4; ++i)
            #pragma unroll
            for (int r = 0; r < 4; ++r) {
                int m = m0 + i * 16 + quad * 4 + r;
                if (m >= M) continue;
                #pragma unroll
                for (int j = 0; j < 2; ++j) {
                    int g = wn + j * 16 + lr;
                    long idx = (long)m * 128 + g;
                    float a0 = accS[0][i][j][r] + b2[g];
                    float a1 = accS[1][i][j][r] + b2[128 + g];
                    float a2 = accS[2][i][j][r] + b2[256 + g];
                    float u0 = uv[idx], u1 = uv[SP + idx], u2 = uv[2 * SP + idx];
                    float w0 = vv[idx], w1 = vv[SP + idx], w2 = vv[2 * SP + idx];
                    float dot = u0 * w0 + u1 * w1 + u2 * w2;
                    s_out[idx] = s[idx] + dot * a1 + a2;
                    float x0 = vbuf[idx]          + u0 * a0;
                    float x1 = vbuf[SP + idx]     + u1 * a0;
                    float x2 = vbuf[2 * SP + idx] + u2 * a0;
                    if (outv) {
                        outv[idx * 3 + 0] = x0;
                        outv[idx * 3 + 1] = x1;
                        outv[idx * 3 + 2] = x2;
                    } else {
                        vbuf[idx]          = x0;
                        vbuf[SP + idx]     = x1;
                        vbuf[2 * SP + idx] = x2;
                    }
                }
            }
    }
}

// ---------------------------------------------------------------------------
// Pre-split MFMA GEMM (UV only): dual weights, fp32 C0/C1 routing by n-tile.
// ---------------------------------------------------------------------------
__global__ __launch_bounds__(256) void gemm_ps_kernel(
    const ushort_t* __restrict__ Ahg, const ushort_t* __restrict__ Alg,
    const ushort_t* __restrict__ Whi, const ushort_t* __restrict__ Wlo,
    const ushort_t* __restrict__ W2h, const ushort_t* __restrict__ W2l,
    float* __restrict__ C0, float* __restrict__ C1,
    int M, int K)
{
    __shared__ __align__(16) ushort_t Ah[128 * 40];
    __shared__ __align__(16) ushort_t Al[128 * 40];
    __shared__ __align__(16) ushort_t Wh[128 * 40];
    __shared__ __align__(16) ushort_t Wl[128 * 40];
    const int t    = threadIdx.x;
    const int m0   = blockIdx.x * 128;
    const int nt   = blockIdx.y;          // 0 -> U/C0, 1 -> V/C1
    const int wv   = t >> 6;
    const int lane = t & 63;
    const int wm   = (wv >> 1) * 64;
    const int wn   = (wv & 1) * 64;
    const int lr   = lane & 15;
    const int lk   = (lane >> 4) * 8;
    const int srow = t >> 2;
    const int scol = (t & 3) * 8;
    const ushort_t* Wsh = nt ? W2h : Whi;
    const ushort_t* Wsl = nt ? W2l : Wlo;

    floatx4 acc[4][4] = {};

    for (int k0 = 0; k0 < K; k0 += 32) {
        #pragma unroll
        for (int h = 0; h < 2; ++h) {
            int r = srow + h * 64;
            int m = m0 + r; if (m >= M) m = M - 1;
            *(uint4*)(&Ah[r * 40 + scol]) =
                *(const uint4*)(Ahg + (long)m * K + k0 + scol);
            *(uint4*)(&Al[r * 40 + scol]) =
                *(const uint4*)(Alg + (long)m * K + k0 + scol);
            *(uint4*)(&Wh[r * 40 + scol]) =
                *(const uint4*)(Wsh + (long)r * K + k0 + scol);
            *(uint4*)(&Wl[r * 40 + scol]) =
                *(const uint4*)(Wsl + (long)r * K + k0 + scol);
        }
        __syncthreads();
        short8 ah[4], al[4], wh[4], wl[4];
        #pragma unroll
        for (int i = 0; i < 4; ++i) {
            ah[i] = *(const short8*)(&Ah[(wm + i * 16 + lr) * 40 + lk]);
            al[i] = *(const short8*)(&Al[(wm + i * 16 + lr) * 40 + lk]);
            wh[i] = *(const short8*)(&Wh[(wn + i * 16 + lr) * 40 + lk]);
            wl[i] = *(const short8*)(&Wl[(wn + i * 16 + lr) * 40 + lk]);
        }
        #pragma unroll
        for (int i = 0; i < 4; ++i)
            #pragma unroll
            for (int j = 0; j < 4; ++j) {
                acc[i][j] = __builtin_amdgcn_mfma_f32_16x16x32_bf16(
                    ah[i], wh[j], acc[i][j], 0, 0, 0);
                acc[i][j] = __builtin_amdgcn_mfma_f32_16x16x32_bf16(
                    ah[i], wl[j], acc[i][j], 0, 0, 0);
                acc[i][j] = __builtin_amdgcn_mfma_f32_16x16x32_bf16(
                    al[i], wh[j], acc[i][j], 0, 0, 0);
            }
        __syncthreads();
    }

    float* C = nt ? C1 : C0;
    #pragma unroll
    for (int i = 0; i < 4; ++i)
        #pragma unroll
        for (int r = 0; r < 4; ++r) {
            int m = m0 + wm + i * 16 + (lane >> 4) * 4 + r;
            if (m >= M) continue;
            #pragma unroll
            for (int j = 0; j < 4; ++j) {
                int n = wn + j * 16 + lr;
                C[(long)m * 128 + n] = acc[i][j][r];
            }
        }
}

// ---------------------------------------------------------------------------
__global__ __launch_bounds__(256) void split_kernel(
    const float* __restrict__ src, ushort_t* __restrict__ hi,
    ushort_t* __restrict__ lo, int n)
{
    int i = blockIdx.x * blockDim.x + threadIdx.x;
    if (i >= n) return;
    float x = src[i];
    unsigned short h = f2b(x);
    hi[i] = h;
    lo[i] = f2b(x - b2f(h));
}

// ---------------------------------------------------------------------------
// CSR build
// ---------------------------------------------------------------------------
__global__ __launch_bounds__(256) void hist_kernel(
    const int* __restrict__ nbr, int* __restrict__ deg, int Ed)
{
    int e = blockIdx.x * blockDim.x + threadIdx.x;
    if (e >= Ed) return;
    int E = Ed >> 1;
    int i = (e < E) ? nbr[2 * e] : nbr[2 * (e - E) + 1];
    atomicAdd(&deg[i], 1);
}

__device__ inline int wave_incl_scan(int x, int lane)
{
    #pragma unroll
    for (int s = 1; s < 64; s <<= 1) {
        int y = __shfl_up(x, s, 64);
        if (lane >= s) x += y;
    }
    return x;
}

__global__ __launch_bounds__(1024) void scan_kernel(
    const int* __restrict__ deg, int* __restrict__ off,
    int* __restrict__ cursor, int N)
{
    __shared__ int wsum[16];
    __shared__ int carry_s;
    const int t = threadIdx.x;
    const int lane = t & 63;
    const int w = t >> 6;
    if (t == 0) { carry_s = 0; off[0] = 0; }
    __syncthreads();
    for (int base = 0; base < N; base += 1024) {
        int i = base + t;
        int x = (i < N) ? deg[i] : 0;
        int sc = wave_incl_scan(x, lane);
        if (lane == 63) wsum[w] = sc;
        __syncthreads();
        if (w == 0) {
            int v = (lane < 16) ? wsum[lane] : 0;
            int vs = wave_incl_scan(v, lane);
            if (lane < 16) wsum[lane] = vs;
        }
        __syncthreads();
        int waveoff = (w > 0) ? wsum[w - 1] : 0;
        int inc = sc + waveoff + carry_s;
        if (i < N) { off[i + 1] = inc; cursor[i] = inc - x; }
        __syncthreads();
        if (t == 1023) carry_s = inc;
        __syncthreads();
    }
}

__global__ __launch_bounds__(256) void scatter_geom_kernel(
    const int* __restrict__ nbr, const float* __restrict__ xyz,
    int* __restrict__ cursor, int* __restrict__ csr_j,
    float* __restrict__ csr_env, float* __restrict__ csr_unit,
    float* __restrict__ csr_rbfe, int Ed)
{
    int e = blockIdx.x * blockDim.x + threadIdx.x;
    if (e >= Ed) return;
    int E = Ed >> 1;
    int i, j;
    if (e < E) { i = nbr[2 * e];         j = nbr[2 * e + 1]; }
    else       { int u = e - E; i = nbr[2 * u + 1]; j = nbr[2 * u]; }

    int p = atomicAdd(&cursor[i], 1);
    csr_j[p] = j;

    float rx = xyz[3 * j + 0] - xyz[3 * i + 0];
    float ry = xyz[3 * j + 1] - xyz[3 * i + 1];
    float rz = xyz[3 * j + 2] - xyz[3 * i + 2];
    float d   = sqrtf(rx * rx + ry * ry + rz * rz);
    float inv = 1.f / d;
    csr_unit[3 * p + 0] = rx * inv;
    csr_unit[3 * p + 1] = ry * inv;
    csr_unit[3 * p + 2] = rz * inv;
    float ev = (d < 20.f) ? 0.5f * (__cosf(PI_F * d / 20.f) + 1.f) : 0.f;
    csr_env[p] = ev;
    float base = PI_F * d / 20.f;
    #pragma unroll
    for (int k = 0; k < NRBF; ++k)
        csr_rbfe[(long)p * NRBF + k] = ev * __sinf((float)(k + 1) * base) * inv;
}

// ---------------------------------------------------------------------------
// Edge aggregation — EXACT R0 structure (proven best: VGPR 52, occ 37%,
// ~108 us). Five variants (LDS coeffs, packed gathers, persistent blocks,
// pair-unroll) all regressed via lower occupancy; do not touch.
// ---------------------------------------------------------------------------
__global__ __launch_bounds__(128) void edge_aggr_kernel(
    const int* __restrict__ off, const int* __restrict__ csr_j,
    const float* __restrict__ csr_env, const float* __restrict__ csr_unit,
    const float* __restrict__ csr_rbfe,
    const ushort_t* __restrict__ phib, const float* __restrict__ vold,
    const float* __restrict__ distW, const float* __restrict__ distb,
    float* __restrict__ s, float* __restrict__ vnew,
    ushort_t* __restrict__ vnh, ushort_t* __restrict__ vnl, int N, int SP)
{
    const int f = threadIdx.x;
    float w0c[NRBF], w1c[NRBF], w2c[NRBF];
    const float b0 = distb[f];
    const float b1 = distb[128 + f];
    const float b2 = distb[256 + f];
    #pragma unroll
    for (int k = 0; k < NRBF; ++k) {
        w0c[k] = distW[(long)f * NRBF + k];
        w1c[k] = distW[(long)(128 + f) * NRBF + k];
        w2c[k] = distW[(long)(256 + f) * NRBF + k];
    }

    for (int node = blockIdx.x; node < N; node += gridDim.x) {
        const int p0 = off[node], p1 = off[node + 1];
        float ssum = 0.f, v0 = 0.f, v1 = 0.f, v2 = 0.f;
        for (int p = p0; p < p1; ++p) {
            int j = csr_j[p];
            float ev = csr_env[p];
            float ux = csr_unit[3 * p + 0];
            float uy = csr_unit[3 * p + 1];
            float uz = csr_unit[3 * p + 2];
            const float* rb = csr_rbfe + (long)p * NRBF;
            float w0 = ev * b0, w1 = ev * b1, w2 = ev * b2;
            #pragma unroll
            for (int k = 0; k < NRBF; ++k) {
                float r = rb[k];
                w0 += r * w0c[k];
                w1 += r * w1c[k];
                w2 += r * w2c[k];
            }
            long jb = (long)j * 384;
            float i0 = b2f(phib[jb + f])       * w0;
            float i1 = b2f(phib[jb + 128 + f]) * w1;
            float i2 = b2f(phib[jb + 256 + f]) * w2;
            long jv = (long)j * FEAT + f;
            ssum += i1;
            v0 += i2 * ux + i0 * vold[jv];
            v1 += i2 * uy + i0 * vold[SP + jv];
            v2 += i2 * uz + i0 * vold[2 * SP + jv];
        }
        long iv = (long)node * FEAT + f;
        s[iv] += ssum;
        float n0 = vold[iv]          + v0;
        float n1 = vold[SP + iv]     + v1;
        float n2 = vold[2 * SP + iv] + v2;
        vnew[iv]          = n0;
        vnew[SP + iv]     = n1;
        vnew[2 * SP + iv] = n2;
        unsigned short h0 = f2b(n0), h1 = f2b(n1), h2 = f2b(n2);
        vnh[iv]          = h0;  vnl[iv]          = f2b(n0 - b2f(h0));
        vnh[SP + iv]     = h1;  vnl[SP + iv]     = f2b(n1 - b2f(h1));
        vnh[2 * SP + iv] = h2;  vnl[2 * SP + iv] = f2b(n2 - b2f(h2));
    }
}

// ---------------------------------------------------------------------------
// Elementwise kernels
// ---------------------------------------------------------------------------
__global__ __launch_bounds__(256) void init_s_kernel(
    const float* __restrict__ cg_s, float* __restrict__ s,
    float* __restrict__ vA, int nS, int nV)
{
    int idx = blockIdx.x * blockDim.x + threadIdx.x;
    if (idx < nS) s[idx] = cg_s[idx];
    if (idx < nV) vA[idx] = 0.f;
}

// ---------------------------------------------------------------------------
extern "C" void kernel_launch(void* const* d_in, const int* in_sizes, int n_in,
                              void* d_out, int out_size, void* d_ws, size_t ws_size,
                              hipStream_t stream)
{
    const float* xyz     = (const float*)d_in[0];
    const int*   nbr     = (const int*)  d_in[1];
    const float* cg_s    = (const float*)d_in[2];
    const float* msg_W1  = (const float*)d_in[3];
    const float* msg_b1  = (const float*)d_in[4];
    const float* msg_W2  = (const float*)d_in[5];
    const float* msg_b2  = (const float*)d_in[6];
    const float* dist_W  = (const float*)d_in[7];
    const float* dist_b  = (const float*)d_in[8];
    const float* upd_U   = (const float*)d_in[9];
    const float* upd_V   = (const float*)d_in[10];
    const float* upd_sW1 = (const float*)d_in[11];
    const float* upd_sb1 = (const float*)d_in[12];
    const float* upd_sW2 = (const float*)d_in[13];
    const float* upd_sb2 = (const float*)d_in[14];

    const int E  = in_sizes[1] / 2;
    const int Ed = 2 * E;
    const int N  = in_sizes[2] / FEAT;
    const int SP = N * FEAT;

    float* s    = (float*)d_out;
    float* outv = (float*)d_out + (long)SP;

    // workspace carve-up
    float* w = (float*)d_ws;
    size_t off_ = 0;
    auto alloc = [&](size_t nelem) {
        float* p = w + off_;
        off_ += (nelem + 255) & ~(size_t)255;
        return p;
    };
    auto allocb = [&](size_t nelem) {
        return (ushort_t*)alloc((nelem + 1) / 2);
    };
    int*   deg      = (int*)alloc((size_t)N);
    int*   off      = (int*)alloc((size_t)N + 1);
    int*   cursor   = (int*)alloc((size_t)N);
    int*   csr_j    = (int*)alloc((size_t)Ed);
    float* csr_env  = alloc((size_t)Ed);
    float* csr_unit = alloc((size_t)Ed * 3);
    float* csr_rbfe = alloc((size_t)Ed * NRBF);
    float* u_v      = alloc((size_t)3 * SP);
    float* v_v      = alloc((size_t)3 * SP);
    float* vA       = alloc((size_t)3 * SP);
    float* vB       = alloc((size_t)3 * SP);
    ushort_t* phi_b = allocb((size_t)N * 384);
    ushort_t* vnh   = allocb((size_t)3 * SP);
    ushort_t* vnl   = allocb((size_t)3 * SP);
    const int n1 = NCONV * FEAT * FEAT;
    const int n2 = NCONV * 3 * FEAT * FEAT;
    const int n3 = NCONV * FEAT * 2 * FEAT;
    ushort_t* w1h  = allocb((size_t)n1);
    ushort_t* w1l  = allocb((size_t)n1);
    ushort_t* w2h  = allocb((size_t)n2);
    ushort_t* w2l  = allocb((size_t)n2);
    ushort_t* uh   = allocb((size_t)n1);
    ushort_t* ul   = allocb((size_t)n1);
    ushort_t* vh   = allocb((size_t)n1);
    ushort_t* vl   = allocb((size_t)n1);
    ushort_t* sw1h = allocb((size_t)n3);
    ushort_t* sw1l = allocb((size_t)n3);
    ushort_t* sw2h = allocb((size_t)n2);
    ushort_t* sw2l = allocb((size_t)n2);
    (void)ws_size; (void)n_in; (void)out_size;

    // weight split (once per launch)
    split_kernel<<<(n1 + 255) / 256, 256, 0, stream>>>(msg_W1, w1h, w1l, n1);
    split_kernel<<<(n2 + 255) / 256, 256, 0, stream>>>(msg_W2, w2h, w2l, n2);
    split_kernel<<<(n1 + 255) / 256, 256, 0, stream>>>(upd_U, uh, ul, n1);
    split_kernel<<<(n1 + 255) / 256, 256, 0, stream>>>(upd_V, vh, vl, n1);
    split_kernel<<<(n3 + 255) / 256, 256, 0, stream>>>(upd_sW1, sw1h, sw1l, n3);
    split_kernel<<<(n2 + 255) / 256, 256, 0, stream>>>(upd_sW2, sw2h, sw2l, n2);

    // init s <- cg_s, vA <- 0
    {
        int n = 3 * SP;
        init_s_kernel<<<(n + 255) / 256, 256, 0, stream>>>(cg_s, s, vA, SP, n);
    }

    // CSR build (once per launch)
    hipMemsetAsync(deg, 0, (size_t)N * sizeof(int), stream);
    hist_kernel<<<(Ed + 255) / 256, 256, 0, stream>>>(nbr, deg, Ed);
    scan_kernel<<<1, 1024, 0, stream>>>(deg, off, cursor, N);
    scatter_geom_kernel<<<(Ed + 255) / 256, 256, 0, stream>>>(
        nbr, xyz, cursor, csr_j, csr_env, csr_unit, csr_rbfe, Ed);

    float* vold = vA;
    float* vnew = vB;
    dim3 gM((N + 63) / 64, 1);
    dim3 gUV((3 * N + 127) / 128, 2);

    for (int l = 0; l < NCONV; ++l) {
        const float* b1  = msg_b1  + (long)l * FEAT;
        const float* b2  = msg_b2  + (long)l * 3 * FEAT;
        const float* dW  = dist_W  + (long)l * 3 * FEAT * NRBF;
        const float* db  = dist_b  + (long)l * 3 * FEAT;
        const float* sb1 = upd_sb1 + (long)l * FEAT;
        const float* sb2 = upd_sb2 + (long)l * 3 * FEAT;
        const long o1 = (long)l * FEAT * FEAT;
        const long o2 = (long)l * 3 * FEAT * FEAT;
        const long o3 = (long)l * FEAT * 2 * FEAT;

        // fused phi-MLP: s -> (h in LDS) -> phi_b (bf16 hi)
        mlp_fused_kernel<0><<<gM, 256, 0, stream>>>(
            s, nullptr, w1h + o1, w1l + o1, b1, w2h + o2, w2l + o2, b2,
            phi_b, nullptr, nullptr, nullptr, nullptr, N, FEAT, SP);

        // atomic-free message aggregation (exact R0)
        edge_aggr_kernel<<<N, 128, 0, stream>>>(
            off, csr_j, csr_env, csr_unit, csr_rbfe, phi_b, vold,
            dW, db, s, vnew, vnh, vnl, N, SP);

        // u_v / v_v in one dispatch (y=0 -> U, y=1 -> V)
        gemm_ps_kernel<<<gUV, 256, 0, stream>>>(
            vnh, vnl, uh + o1, ul + o1, vh + o1, vl + o1,
            u_v, v_v, 3 * N, FEAT);

        // fused gate-MLP + update epilogue: [s | norm(v_v)] -> a -> s,v update
        float* ov = (l == NCONV - 1) ? outv : nullptr;
        mlp_fused_kernel<1><<<gM, 256, 0, stream>>>(
            s, v_v, sw1h + o3, sw1l + o3, sb1, sw2h + o2, sw2l + o2, sb2,
            nullptr, u_v, s, vnew, ov, N, 2 * FEAT, SP);

        float* tmp = vold; vold = vnew; vnew = tmp;
    }
}

// Round 8
// 768.824 us; speedup vs baseline: 1.4774x; 1.0316x over previous
//
#include <hip/hip_runtime.h>
#include <math.h>

#define FEAT 128
#define NRBF 20
#define NCONV 3
#define PI_F 3.14159265358979323846f

typedef __attribute__((ext_vector_type(8))) short short8;
typedef __attribute__((ext_vector_type(4))) float floatx4;
typedef unsigned short ushort_t;

__device__ inline float b2f(unsigned short u) {
    union { unsigned int i; float f; } c; c.i = ((unsigned int)u) << 16; return c.f;
}
__device__ inline unsigned short f2b(float x) {
    union { float f; unsigned int i; } c; c.f = x;
    unsigned int u = c.i;
    return (unsigned short)((u + 0x7fffu + ((u >> 16) & 1u)) >> 16);
}

// ---------------------------------------------------------------------------
// Fused 2-layer MLP: out[M,384] = silu(A1 @ W1^T + b1) @ W2^T + b2
// A1 = s[M,128] (phi mode) or [s | norm(vv)] [M,256] (gate mode).
// BM=64, 256 thr = 4 waves, per-wave 64x32 slice (acc[4][2]); LDS 64 KB ->
// 2 blocks/CU; grid ceil(M/64) covers all 256 CUs.  (R6 structure, proven.)
// FUSED=1 (gate mode): keeps stage-2 accumulators across all 3 n-tiles and
// applies the update_sv arithmetic in the epilogue (R7, proven: -63 us).
// ---------------------------------------------------------------------------
template<int FUSED>
__global__ __launch_bounds__(256, 2) void mlp_fused_kernel(
    const float* __restrict__ s, const float* __restrict__ vv,
    const ushort_t* __restrict__ W1h, const ushort_t* __restrict__ W1l,
    const float* __restrict__ b1,
    const ushort_t* __restrict__ W2h, const ushort_t* __restrict__ W2l,
    const float* __restrict__ b2,
    ushort_t* __restrict__ out_b,
    const float* __restrict__ uv,      // FUSED: u_v planar 3xSP
    float* s_out, float* vbuf,         // FUSED: s (rw), v (rw, planar 3xSP)
    float* outv,                       // FUSED last layer: interleaved out
    int M, int K1, int SP)
{
    __shared__ __align__(16) ushort_t Ah[64 * 40];
    __shared__ __align__(16) ushort_t Al[64 * 40];
    __shared__ __align__(16) ushort_t Wh[128 * 40];
    __shared__ __align__(16) ushort_t Wl[128 * 40];
    __shared__ __align__(16) ushort_t Hh[64 * 136];
    __shared__ __align__(16) ushort_t Hl[64 * 136];

    const int t    = threadIdx.x;
    const int m0   = blockIdx.x * 64;
    const int wv   = t >> 6;
    const int lane = t & 63;
    const int wn   = wv * 32;         // wave's 32-col slice
    const int lr   = lane & 15;
    const int lk   = (lane >> 4) * 8;
    const int quad = lane >> 4;
    const int arow = t >> 3;          // 0..31, 2 passes of 32 rows
    const int acol = (t & 7) * 4;     // fp32 x4
    const int wrow = t >> 2;          // 0..63, 2 passes of 64 rows
    const int wcol = (t & 3) * 8;     // ushort x8

    floatx4 acc[4][2] = {};

    // ---- stage 1: h = silu(A1 @ W1^T + b1) ----
    for (int k0 = 0; k0 < K1; k0 += 32) {
        #pragma unroll
        for (int h = 0; h < 2; ++h) {
            int r = arow + h * 32;
            int m = m0 + r; if (m >= M) m = M - 1;   // clamp tail (in-block)
            float xs[4];
            if (k0 < 128) {
                float4 av = *(const float4*)(s + (long)m * 128 + k0 + acol);
                xs[0] = av.x; xs[1] = av.y; xs[2] = av.z; xs[3] = av.w;
            } else {
                long base = (long)m * 128 + (k0 - 128 + acol);
                float4 a0 = *(const float4*)(vv + base);
                float4 a1 = *(const float4*)(vv + (long)SP + base);
                float4 a2 = *(const float4*)(vv + 2 * (long)SP + base);
                xs[0] = sqrtf(a0.x * a0.x + a1.x * a1.x + a2.x * a2.x);
                xs[1] = sqrtf(a0.y * a0.y + a1.y * a1.y + a2.y * a2.y);
                xs[2] = sqrtf(a0.z * a0.z + a1.z * a1.z + a2.z * a2.z);
                xs[3] = sqrtf(a0.w * a0.w + a1.w * a1.w + a2.w * a2.w);
            }
            unsigned short hh[4], ll[4];
            #pragma unroll
            for (int q = 0; q < 4; ++q) {
                hh[q] = f2b(xs[q]);
                ll[q] = f2b(xs[q] - b2f(hh[q]));
            }
            *(ushort4*)(&Ah[r * 40 + acol]) = make_ushort4(hh[0], hh[1], hh[2], hh[3]);
            *(ushort4*)(&Al[r * 40 + acol]) = make_ushort4(ll[0], ll[1], ll[2], ll[3]);
        }
        #pragma unroll
        for (int h = 0; h < 2; ++h) {
            int r = wrow + h * 64;
            *(uint4*)(&Wh[r * 40 + wcol]) =
                *(const uint4*)(W1h + (long)r * K1 + k0 + wcol);
            *(uint4*)(&Wl[r * 40 + wcol]) =
                *(const uint4*)(W1l + (long)r * K1 + k0 + wcol);
        }
        __syncthreads();
        short8 af[4], alf[4], wf[2], wlf[2];
        #pragma unroll
        for (int i = 0; i < 4; ++i) {
            af[i]  = *(const short8*)(&Ah[(i * 16 + lr) * 40 + lk]);
            alf[i] = *(const short8*)(&Al[(i * 16 + lr) * 40 + lk]);
        }
        #pragma unroll
        for (int j = 0; j < 2; ++j) {
            wf[j]  = *(const short8*)(&Wh[(wn + j * 16 + lr) * 40 + lk]);
            wlf[j] = *(const short8*)(&Wl[(wn + j * 16 + lr) * 40 + lk]);
        }
        #pragma unroll
        for (int i = 0; i < 4; ++i)
            #pragma unroll
            for (int j = 0; j < 2; ++j) {
                acc[i][j] = __builtin_amdgcn_mfma_f32_16x16x32_bf16(
                    af[i], wf[j], acc[i][j], 0, 0, 0);
                acc[i][j] = __builtin_amdgcn_mfma_f32_16x16x32_bf16(
                    af[i], wlf[j], acc[i][j], 0, 0, 0);
                acc[i][j] = __builtin_amdgcn_mfma_f32_16x16x32_bf16(
                    alf[i], wf[j], acc[i][j], 0, 0, 0);
            }
        __syncthreads();
    }

    // stage-1 epilogue -> h in LDS (hi/lo), C/D layout col=lane&15, row=quad*4+r
    #pragma unroll
    for (int i = 0; i < 4; ++i)
        #pragma unroll
        for (int r = 0; r < 4; ++r) {
            int mrow = i * 16 + quad * 4 + r;
            #pragma unroll
            for (int j = 0; j < 2; ++j) {
                int kcol = wn + j * 16 + lr;
                float x = acc[i][j][r] + b1[kcol];
                x *= 1.f / (1.f + __expf(-x));
                unsigned short hh = f2b(x);
                Hh[mrow * 136 + kcol] = hh;
                Hl[mrow * 136 + kcol] = f2b(x - b2f(hh));
            }
        }

    // ---- stage 2: 3 n-tiles of 128; FUSED keeps all accumulators ----
    floatx4 accS[3][4][2];
    #pragma unroll
    for (int nt = 0; nt < 3; ++nt) {
        floatx4 a2c[4][2] = {};
        for (int k0 = 0; k0 < 128; k0 += 32) {
            __syncthreads();   // guard Wh/Wl overwrite (and H writes on 1st pass)
            #pragma unroll
            for (int h = 0; h < 2; ++h) {
                int r = wrow + h * 64;
                long wo = (long)(nt * 128 + r) * 128;
                *(uint4*)(&Wh[r * 40 + wcol]) = *(const uint4*)(W2h + wo + k0 + wcol);
                *(uint4*)(&Wl[r * 40 + wcol]) = *(const uint4*)(W2l + wo + k0 + wcol);
            }
            __syncthreads();
            short8 af[4], alf[4], wf[2], wlf[2];
            #pragma unroll
            for (int i = 0; i < 4; ++i) {
                af[i]  = *(const short8*)(&Hh[(i * 16 + lr) * 136 + k0 + lk]);
                alf[i] = *(const short8*)(&Hl[(i * 16 + lr) * 136 + k0 + lk]);
            }
            #pragma unroll
            for (int j = 0; j < 2; ++j) {
                wf[j]  = *(const short8*)(&Wh[(wn + j * 16 + lr) * 40 + lk]);
                wlf[j] = *(const short8*)(&Wl[(wn + j * 16 + lr) * 40 + lk]);
            }
            #pragma unroll
            for (int i = 0; i < 4; ++i)
                #pragma unroll
                for (int j = 0; j < 2; ++j) {
                    a2c[i][j] = __builtin_amdgcn_mfma_f32_16x16x32_bf16(
                        af[i], wf[j], a2c[i][j], 0, 0, 0);
                    a2c[i][j] = __builtin_amdgcn_mfma_f32_16x16x32_bf16(
                        af[i], wlf[j], a2c[i][j], 0, 0, 0);
                    a2c[i][j] = __builtin_amdgcn_mfma_f32_16x16x32_bf16(
                        alf[i], wf[j], a2c[i][j], 0, 0, 0);
                }
        }
        if (FUSED) {
            #pragma unroll
            for (int i = 0; i < 4; ++i)
                #pragma unroll
                for (int j = 0; j < 2; ++j)
                    accS[nt][i][j] = a2c[i][j];
        } else {
            #pragma unroll
            for (int i = 0; i < 4; ++i)
                #pragma unroll
                for (int r = 0; r < 4; ++r) {
                    int m = m0 + i * 16 + quad * 4 + r;
                    if (m >= M) continue;
                    #pragma unroll
                    for (int j = 0; j < 2; ++j) {
                        int n = nt * 128 + wn + j * 16 + lr;
                        out_b[(long)m * 384 + n] = f2b(a2c[i][j][r] + b2[n]);
                    }
                }
        }
    }

    // ---- fused update epilogue (gate mode): update_sv arithmetic in-place ----
    if (FUSED) {
        #pragma unroll
        for (int i = 0; i < 4; ++i)
            #pragma unroll
            for (int r = 0; r < 4; ++r) {
                int m = m0 + i * 16 + quad * 4 + r;
                if (m >= M) continue;
                #pragma unroll
                for (int j = 0; j < 2; ++j) {
                    int g = wn + j * 16 + lr;
                    long idx = (long)m * 128 + g;
                    float a0 = accS[0][i][j][r] + b2[g];
                    float a1 = accS[1][i][j][r] + b2[128 + g];
                    float a2 = accS[2][i][j][r] + b2[256 + g];
                    float u0 = uv[idx], u1 = uv[SP + idx], u2 = uv[2 * SP + idx];
                    float w0 = vv[idx], w1 = vv[SP + idx], w2 = vv[2 * SP + idx];
                    float dot = u0 * w0 + u1 * w1 + u2 * w2;
                    s_out[idx] = s[idx] + dot * a1 + a2;
                    float x0 = vbuf[idx]          + u0 * a0;
                    float x1 = vbuf[SP + idx]     + u1 * a0;
                    float x2 = vbuf[2 * SP + idx] + u2 * a0;
                    if (outv) {
                        outv[idx * 3 + 0] = x0;
                        outv[idx * 3 + 1] = x1;
                        outv[idx * 3 + 2] = x2;
                    } else {
                        vbuf[idx]          = x0;
                        vbuf[SP + idx]     = x1;
                        vbuf[2 * SP + idx] = x2;
                    }
                }
            }
    }
}

// ---------------------------------------------------------------------------
// Pre-split MFMA GEMM (UV only): dual weights, fp32 C0/C1 routing by n-tile.
// ---------------------------------------------------------------------------
__global__ __launch_bounds__(256) void gemm_ps_kernel(
    const ushort_t* __restrict__ Ahg, const ushort_t* __restrict__ Alg,
    const ushort_t* __restrict__ Whi, const ushort_t* __restrict__ Wlo,
    const ushort_t* __restrict__ W2h, const ushort_t* __restrict__ W2l,
    float* __restrict__ C0, float* __restrict__ C1,
    int M, int K)
{
    __shared__ __align__(16) ushort_t Ah[128 * 40];
    __shared__ __align__(16) ushort_t Al[128 * 40];
    __shared__ __align__(16) ushort_t Wh[128 * 40];
    __shared__ __align__(16) ushort_t Wl[128 * 40];
    const int t    = threadIdx.x;
    const int m0   = blockIdx.x * 128;
    const int nt   = blockIdx.y;          // 0 -> U/C0, 1 -> V/C1
    const int wv   = t >> 6;
    const int lane = t & 63;
    const int wm   = (wv >> 1) * 64;
    const int wn   = (wv & 1) * 64;
    const int lr   = lane & 15;
    const int lk   = (lane >> 4) * 8;
    const int srow = t >> 2;
    const int scol = (t & 3) * 8;
    const ushort_t* Wsh = nt ? W2h : Whi;
    const ushort_t* Wsl = nt ? W2l : Wlo;

    floatx4 acc[4][4] = {};

    for (int k0 = 0; k0 < K; k0 += 32) {
        #pragma unroll
        for (int h = 0; h < 2; ++h) {
            int r = srow + h * 64;
            int m = m0 + r; if (m >= M) m = M - 1;
            *(uint4*)(&Ah[r * 40 + scol]) =
                *(const uint4*)(Ahg + (long)m * K + k0 + scol);
            *(uint4*)(&Al[r * 40 + scol]) =
                *(const uint4*)(Alg + (long)m * K + k0 + scol);
            *(uint4*)(&Wh[r * 40 + scol]) =
                *(const uint4*)(Wsh + (long)r * K + k0 + scol);
            *(uint4*)(&Wl[r * 40 + scol]) =
                *(const uint4*)(Wsl + (long)r * K + k0 + scol);
        }
        __syncthreads();
        short8 ah[4], al[4], wh[4], wl[4];
        #pragma unroll
        for (int i = 0; i < 4; ++i) {
            ah[i] = *(const short8*)(&Ah[(wm + i * 16 + lr) * 40 + lk]);
            al[i] = *(const short8*)(&Al[(wm + i * 16 + lr) * 40 + lk]);
            wh[i] = *(const short8*)(&Wh[(wn + i * 16 + lr) * 40 + lk]);
            wl[i] = *(const short8*)(&Wl[(wn + i * 16 + lr) * 40 + lk]);
        }
        #pragma unroll
        for (int i = 0; i < 4; ++i)
            #pragma unroll
            for (int j = 0; j < 4; ++j) {
                acc[i][j] = __builtin_amdgcn_mfma_f32_16x16x32_bf16(
                    ah[i], wh[j], acc[i][j], 0, 0, 0);
                acc[i][j] = __builtin_amdgcn_mfma_f32_16x16x32_bf16(
                    ah[i], wl[j], acc[i][j], 0, 0, 0);
                acc[i][j] = __builtin_amdgcn_mfma_f32_16x16x32_bf16(
                    al[i], wh[j], acc[i][j], 0, 0, 0);
            }
        __syncthreads();
    }

    float* C = nt ? C1 : C0;
    #pragma unroll
    for (int i = 0; i < 4; ++i)
        #pragma unroll
        for (int r = 0; r < 4; ++r) {
            int m = m0 + wm + i * 16 + (lane >> 4) * 4 + r;
            if (m >= M) continue;
            #pragma unroll
            for (int j = 0; j < 4; ++j) {
                int n = wn + j * 16 + lr;
                C[(long)m * 128 + n] = acc[i][j][r];
            }
        }
}

// ---------------------------------------------------------------------------
__global__ __launch_bounds__(256) void split_kernel(
    const float* __restrict__ src, ushort_t* __restrict__ hi,
    ushort_t* __restrict__ lo, int n)
{
    int i = blockIdx.x * blockDim.x + threadIdx.x;
    if (i >= n) return;
    float x = src[i];
    unsigned short h = f2b(x);
    hi[i] = h;
    lo[i] = f2b(x - b2f(h));
}

// ---------------------------------------------------------------------------
// CSR build
// ---------------------------------------------------------------------------
__global__ __launch_bounds__(256) void hist_kernel(
    const int* __restrict__ nbr, int* __restrict__ deg, int Ed)
{
    int e = blockIdx.x * blockDim.x + threadIdx.x;
    if (e >= Ed) return;
    int E = Ed >> 1;
    int i = (e < E) ? nbr[2 * e] : nbr[2 * (e - E) + 1];
    atomicAdd(&deg[i], 1);
}

__device__ inline int wave_incl_scan(int x, int lane)
{
    #pragma unroll
    for (int s = 1; s < 64; s <<= 1) {
        int y = __shfl_up(x, s, 64);
        if (lane >= s) x += y;
    }
    return x;
}

__global__ __launch_bounds__(1024) void scan_kernel(
    const int* __restrict__ deg, int* __restrict__ off,
    int* __restrict__ cursor, int N)
{
    __shared__ int wsum[16];
    __shared__ int carry_s;
    const int t = threadIdx.x;
    const int lane = t & 63;
    const int w = t >> 6;
    if (t == 0) { carry_s = 0; off[0] = 0; }
    __syncthreads();
    for (int base = 0; base < N; base += 1024) {
        int i = base + t;
        int x = (i < N) ? deg[i] : 0;
        int sc = wave_incl_scan(x, lane);
        if (lane == 63) wsum[w] = sc;
        __syncthreads();
        if (w == 0) {
            int v = (lane < 16) ? wsum[lane] : 0;
            int vs = wave_incl_scan(v, lane);
            if (lane < 16) wsum[lane] = vs;
        }
        __syncthreads();
        int waveoff = (w > 0) ? wsum[w - 1] : 0;
        int inc = sc + waveoff + carry_s;
        if (i < N) { off[i + 1] = inc; cursor[i] = inc - x; }
        __syncthreads();
        if (t == 1023) carry_s = inc;
        __syncthreads();
    }
}

__global__ __launch_bounds__(256) void scatter_geom_kernel(
    const int* __restrict__ nbr, const float* __restrict__ xyz,
    int* __restrict__ cursor, int* __restrict__ csr_j,
    float* __restrict__ csr_env, float* __restrict__ csr_unit,
    float* __restrict__ csr_rbfe, int Ed)
{
    int e = blockIdx.x * blockDim.x + threadIdx.x;
    if (e >= Ed) return;
    int E = Ed >> 1;
    int i, j;
    if (e < E) { i = nbr[2 * e];         j = nbr[2 * e + 1]; }
    else       { int u = e - E; i = nbr[2 * u + 1]; j = nbr[2 * u]; }

    int p = atomicAdd(&cursor[i], 1);
    csr_j[p] = j;

    float rx = xyz[3 * j + 0] - xyz[3 * i + 0];
    float ry = xyz[3 * j + 1] - xyz[3 * i + 1];
    float rz = xyz[3 * j + 2] - xyz[3 * i + 2];
    float d   = sqrtf(rx * rx + ry * ry + rz * rz);
    float inv = 1.f / d;
    csr_unit[3 * p + 0] = rx * inv;
    csr_unit[3 * p + 1] = ry * inv;
    csr_unit[3 * p + 2] = rz * inv;
    float ev = (d < 20.f) ? 0.5f * (__cosf(PI_F * d / 20.f) + 1.f) : 0.f;
    csr_env[p] = ev;
    float base = PI_F * d / 20.f;
    #pragma unroll
    for (int k = 0; k < NRBF; ++k)
        csr_rbfe[(long)p * NRBF + k] = ev * __sinf((float)(k + 1) * base) * inv;
}

// ---------------------------------------------------------------------------
// Edge aggregation — EXACT R0 inner loop (proven best; five rewrites all
// regressed). R8: ONLY the launch geometry changes: grid 20000 -> 2048, so
// each block's grid-stride loop covers ~10 nodes and the 60 scattered distW
// coefficient loads (previously re-issued by all 20000 blocks: ~614 MB of
// L2 request traffic) amortize 10x. Per-node arithmetic order unchanged ->
// bitwise-identical output.
// ---------------------------------------------------------------------------
__global__ __launch_bounds__(128) void edge_aggr_kernel(
    const int* __restrict__ off, const int* __restrict__ csr_j,
    const float* __restrict__ csr_env, const float* __restrict__ csr_unit,
    const float* __restrict__ csr_rbfe,
    const ushort_t* __restrict__ phib, const float* __restrict__ vold,
    const float* __restrict__ distW, const float* __restrict__ distb,
    float* __restrict__ s, float* __restrict__ vnew,
    ushort_t* __restrict__ vnh, ushort_t* __restrict__ vnl, int N, int SP)
{
    const int f = threadIdx.x;
    float w0c[NRBF], w1c[NRBF], w2c[NRBF];
    const float b0 = distb[f];
    const float b1 = distb[128 + f];
    const float b2 = distb[256 + f];
    #pragma unroll
    for (int k = 0; k < NRBF; ++k) {
        w0c[k] = distW[(long)f * NRBF + k];
        w1c[k] = distW[(long)(128 + f) * NRBF + k];
        w2c[k] = distW[(long)(256 + f) * NRBF + k];
    }

    for (int node = blockIdx.x; node < N; node += gridDim.x) {
        const int p0 = off[node], p1 = off[node + 1];
        float ssum = 0.f, v0 = 0.f, v1 = 0.f, v2 = 0.f;
        for (int p = p0; p < p1; ++p) {
            int j = csr_j[p];
            float ev = csr_env[p];
            float ux = csr_unit[3 * p + 0];
            float uy = csr_unit[3 * p + 1];
            float uz = csr_unit[3 * p + 2];
            const float* rb = csr_rbfe + (long)p * NRBF;
            float w0 = ev * b0, w1 = ev * b1, w2 = ev * b2;
            #pragma unroll
            for (int k = 0; k < NRBF; ++k) {
                float r = rb[k];
                w0 += r * w0c[k];
                w1 += r * w1c[k];
                w2 += r * w2c[k];
            }
            long jb = (long)j * 384;
            float i0 = b2f(phib[jb + f])       * w0;
            float i1 = b2f(phib[jb + 128 + f]) * w1;
            float i2 = b2f(phib[jb + 256 + f]) * w2;
            long jv = (long)j * FEAT + f;
            ssum += i1;
            v0 += i2 * ux + i0 * vold[jv];
            v1 += i2 * uy + i0 * vold[SP + jv];
            v2 += i2 * uz + i0 * vold[2 * SP + jv];
        }
        long iv = (long)node * FEAT + f;
        s[iv] += ssum;
        float n0 = vold[iv]          + v0;
        float n1 = vold[SP + iv]     + v1;
        float n2 = vold[2 * SP + iv] + v2;
        vnew[iv]          = n0;
        vnew[SP + iv]     = n1;
        vnew[2 * SP + iv] = n2;
        unsigned short h0 = f2b(n0), h1 = f2b(n1), h2 = f2b(n2);
        vnh[iv]          = h0;  vnl[iv]          = f2b(n0 - b2f(h0));
        vnh[SP + iv]     = h1;  vnl[SP + iv]     = f2b(n1 - b2f(h1));
        vnh[2 * SP + iv] = h2;  vnl[2 * SP + iv] = f2b(n2 - b2f(h2));
    }
}

// ---------------------------------------------------------------------------
// Elementwise kernels
// ---------------------------------------------------------------------------
__global__ __launch_bounds__(256) void init_s_kernel(
    const float* __restrict__ cg_s, float* __restrict__ s,
    float* __restrict__ vA, int nS, int nV)
{
    int idx = blockIdx.x * blockDim.x + threadIdx.x;
    if (idx < nS) s[idx] = cg_s[idx];
    if (idx < nV) vA[idx] = 0.f;
}

// ---------------------------------------------------------------------------
extern "C" void kernel_launch(void* const* d_in, const int* in_sizes, int n_in,
                              void* d_out, int out_size, void* d_ws, size_t ws_size,
                              hipStream_t stream)
{
    const float* xyz     = (const float*)d_in[0];
    const int*   nbr     = (const int*)  d_in[1];
    const float* cg_s    = (const float*)d_in[2];
    const float* msg_W1  = (const float*)d_in[3];
    const float* msg_b1  = (const float*)d_in[4];
    const float* msg_W2  = (const float*)d_in[5];
    const float* msg_b2  = (const float*)d_in[6];
    const float* dist_W  = (const float*)d_in[7];
    const float* dist_b  = (const float*)d_in[8];
    const float* upd_U   = (const float*)d_in[9];
    const float* upd_V   = (const float*)d_in[10];
    const float* upd_sW1 = (const float*)d_in[11];
    const float* upd_sb1 = (const float*)d_in[12];
    const float* upd_sW2 = (const float*)d_in[13];
    const float* upd_sb2 = (const float*)d_in[14];

    const int E  = in_sizes[1] / 2;
    const int Ed = 2 * E;
    const int N  = in_sizes[2] / FEAT;
    const int SP = N * FEAT;

    float* s    = (float*)d_out;
    float* outv = (float*)d_out + (long)SP;

    // workspace carve-up
    float* w = (float*)d_ws;
    size_t off_ = 0;
    auto alloc = [&](size_t nelem) {
        float* p = w + off_;
        off_ += (nelem + 255) & ~(size_t)255;
        return p;
    };
    auto allocb = [&](size_t nelem) {
        return (ushort_t*)alloc((nelem + 1) / 2);
    };
    int*   deg      = (int*)alloc((size_t)N);
    int*   off      = (int*)alloc((size_t)N + 1);
    int*   cursor   = (int*)alloc((size_t)N);
    int*   csr_j    = (int*)alloc((size_t)Ed);
    float* csr_env  = alloc((size_t)Ed);
    float* csr_unit = alloc((size_t)Ed * 3);
    float* csr_rbfe = alloc((size_t)Ed * NRBF);
    float* u_v      = alloc((size_t)3 * SP);
    float* v_v      = alloc((size_t)3 * SP);
    float* vA       = alloc((size_t)3 * SP);
    float* vB       = alloc((size_t)3 * SP);
    ushort_t* phi_b = allocb((size_t)N * 384);
    ushort_t* vnh   = allocb((size_t)3 * SP);
    ushort_t* vnl   = allocb((size_t)3 * SP);
    const int n1 = NCONV * FEAT * FEAT;
    const int n2 = NCONV * 3 * FEAT * FEAT;
    const int n3 = NCONV * FEAT * 2 * FEAT;
    ushort_t* w1h  = allocb((size_t)n1);
    ushort_t* w1l  = allocb((size_t)n1);
    ushort_t* w2h  = allocb((size_t)n2);
    ushort_t* w2l  = allocb((size_t)n2);
    ushort_t* uh   = allocb((size_t)n1);
    ushort_t* ul   = allocb((size_t)n1);
    ushort_t* vh   = allocb((size_t)n1);
    ushort_t* vl   = allocb((size_t)n1);
    ushort_t* sw1h = allocb((size_t)n3);
    ushort_t* sw1l = allocb((size_t)n3);
    ushort_t* sw2h = allocb((size_t)n2);
    ushort_t* sw2l = allocb((size_t)n2);
    (void)ws_size; (void)n_in; (void)out_size;

    // weight split (once per launch)
    split_kernel<<<(n1 + 255) / 256, 256, 0, stream>>>(msg_W1, w1h, w1l, n1);
    split_kernel<<<(n2 + 255) / 256, 256, 0, stream>>>(msg_W2, w2h, w2l, n2);
    split_kernel<<<(n1 + 255) / 256, 256, 0, stream>>>(upd_U, uh, ul, n1);
    split_kernel<<<(n1 + 255) / 256, 256, 0, stream>>>(upd_V, vh, vl, n1);
    split_kernel<<<(n3 + 255) / 256, 256, 0, stream>>>(upd_sW1, sw1h, sw1l, n3);
    split_kernel<<<(n2 + 255) / 256, 256, 0, stream>>>(upd_sW2, sw2h, sw2l, n2);

    // init s <- cg_s, vA <- 0
    {
        int n = 3 * SP;
        init_s_kernel<<<(n + 255) / 256, 256, 0, stream>>>(cg_s, s, vA, SP, n);
    }

    // CSR build (once per launch)
    hipMemsetAsync(deg, 0, (size_t)N * sizeof(int), stream);
    hist_kernel<<<(Ed + 255) / 256, 256, 0, stream>>>(nbr, deg, Ed);
    scan_kernel<<<1, 1024, 0, stream>>>(deg, off, cursor, N);
    scatter_geom_kernel<<<(Ed + 255) / 256, 256, 0, stream>>>(
        nbr, xyz, cursor, csr_j, csr_env, csr_unit, csr_rbfe, Ed);

    float* vold = vA;
    float* vnew = vB;
    dim3 gM((N + 63) / 64, 1);
    dim3 gUV((3 * N + 127) / 128, 2);
    int edgeGrid = 2048;
    if (edgeGrid > N) edgeGrid = N;

    for (int l = 0; l < NCONV; ++l) {
        const float* b1  = msg_b1  + (long)l * FEAT;
        const float* b2  = msg_b2  + (long)l * 3 * FEAT;
        const float* dW  = dist_W  + (long)l * 3 * FEAT * NRBF;
        const float* db  = dist_b  + (long)l * 3 * FEAT;
        const float* sb1 = upd_sb1 + (long)l * FEAT;
        const float* sb2 = upd_sb2 + (long)l * 3 * FEAT;
        const long o1 = (long)l * FEAT * FEAT;
        const long o2 = (long)l * 3 * FEAT * FEAT;
        const long o3 = (long)l * FEAT * 2 * FEAT;

        // fused phi-MLP: s -> (h in LDS) -> phi_b (bf16 hi)
        mlp_fused_kernel<0><<<gM, 256, 0, stream>>>(
            s, nullptr, w1h + o1, w1l + o1, b1, w2h + o2, w2l + o2, b2,
            phi_b, nullptr, nullptr, nullptr, nullptr, N, FEAT, SP);

        // atomic-free message aggregation (R0 loop, 2048 persistent blocks)
        edge_aggr_kernel<<<edgeGrid, 128, 0, stream>>>(
            off, csr_j, csr_env, csr_unit, csr_rbfe, phi_b, vold,
            dW, db, s, vnew, vnh, vnl, N, SP);

        // u_v / v_v in one dispatch (y=0 -> U, y=1 -> V)
        gemm_ps_kernel<<<gUV, 256, 0, stream>>>(
            vnh, vnl, uh + o1, ul + o1, vh + o1, vl + o1,
            u_v, v_v, 3 * N, FEAT);

        // fused gate-MLP + update epilogue: [s | norm(v_v)] -> a -> s,v update
        float* ov = (l == NCONV - 1) ? outv : nullptr;
        mlp_fused_kernel<1><<<gM, 256, 0, stream>>>(
            s, v_v, sw1h + o3, sw1l + o3, sb1, sw2h + o2, sw2l + o2, sb2,
            nullptr, u_v, s, vnew, ov, N, 2 * FEAT, SP);

        float* tmp = vold; vold = vnew; vnew = tmp;
    }
}